// Round 1
// baseline (2173.709 us; speedup 1.0000x reference)
//
#include <hip/hip_runtime.h>
#include <math.h>

#define IMG   80
#define NPIX  6400      // 80*80
#define NF    64
#define NH    8
#define CDS   32

// ---------------------------------------------------------------------------
// Kernel A: fused Qs (head-summed Q) and K, one thread per (f, p) element.
//   Qs[p*64+f] = sum_h WQ_task[h,f]*(WQ_t_minus_1[h,f]*prev_Q[h,f,p]
//                                    + WQ_x[f]*X[f,p] + BQ[h,f]) + BQ_task[h,f]
//   K [p*64+f] = WK_task[f]*(WK_x[f]*X[f,p] + BK[f]) + BK_task[f]
// Both stored n-major ([pixel][feature]) for the attention kernel.
// ---------------------------------------------------------------------------
__global__ __launch_bounds__(256)
void prep_qk(const float* __restrict__ X,
             const float* __restrict__ WQ_task, const float* __restrict__ BQ_task,
             const float* __restrict__ WK_task, const float* __restrict__ BK_task,
             const float* __restrict__ WQ_t_minus_1, const float* __restrict__ WQ_x,
             const float* __restrict__ BQ,
             const float* __restrict__ WK_x, const float* __restrict__ BK,
             const float* __restrict__ prev_Q,
             float* __restrict__ Qs, float* __restrict__ Kt) {
    int idx = blockIdx.x * 256 + threadIdx.x;
    if (idx >= NF * NPIX) return;
    int f = idx / NPIX;
    int p = idx - f * NPIX;
    float x = X[idx];

    // K
    float kv = WK_task[f] * (WK_x[f] * x + BK[f]) + BK_task[f];
    Kt[p * NF + f] = kv;

    // Qs (sum over heads)
    float wqx_x = WQ_x[f] * x;
    float acc = 0.f;
#pragma unroll
    for (int h = 0; h < NH; ++h) {
        int hf = h * NF + f;
        float inner = WQ_t_minus_1[hf] * prev_Q[hf * NPIX + p] + wqx_x + BQ[hf];
        acc += WQ_task[hf] * inner + BQ_task[hf];
    }
    Qs[p * NF + f] = acc;
}

// ---------------------------------------------------------------------------
// Kernel B: V = WV_task * (conv3x3(X) + conv_bias) + BV_task, one thread per
// (c, p).  Stored n-major: Vt[p*32 + c].
// ---------------------------------------------------------------------------
__global__ __launch_bounds__(256)
void prep_v(const float* __restrict__ X,
            const float* __restrict__ Wc,    // (32, 64, 3, 3) OIHW
            const float* __restrict__ bc,    // (32,)
            const float* __restrict__ WV_task, const float* __restrict__ BV_task,
            float* __restrict__ Vt) {
    int idx = blockIdx.x * 256 + threadIdx.x;
    if (idx >= CDS * NPIX) return;
    int c = idx / NPIX;
    int p = idx - c * NPIX;
    int x0 = p / IMG, y0 = p - (p / IMG) * IMG;

    float acc = 0.f;
    for (int dx = -1; dx <= 1; ++dx) {
        int xx = x0 + dx;
        if (xx < 0 || xx >= IMG) continue;
        for (int dy = -1; dy <= 1; ++dy) {
            int yy = y0 + dy;
            if (yy < 0 || yy >= IMG) continue;
            const float* wp = Wc + c * (NF * 9) + (dx + 1) * 3 + (dy + 1);
            const float* xp = X + xx * IMG + yy;
#pragma unroll
            for (int i = 0; i < NF; ++i)
                acc = fmaf(xp[i * NPIX], wp[i * 9], acc);
        }
    }
    Vt[p * CDS + c] = WV_task[c] * (acc + bc[c]) + BV_task[c];
}

// ---------------------------------------------------------------------------
// Kernel C: fused attention.  8 queries per block (256 threads); 32 lanes per
// query, each lane owns keys n = jn (mod 32) with an independent online
// softmax state (m, l, acc[32]); states merged at the end with a width-32
// shfl_xor butterfly.  K/V are n-major so each lane does float4 loads.
// ---------------------------------------------------------------------------
__global__ __launch_bounds__(256)
void attn_fused(const float* __restrict__ Qs, const float* __restrict__ Kt,
                const float* __restrict__ Vt, float* __restrict__ out) {
    int tid = threadIdx.x;
    int q  = blockIdx.x * 8 + (tid >> 5);
    int jn = tid & 31;

    // load this query's 64 features into registers (broadcast across 32 lanes)
    float Qreg[NF];
#pragma unroll
    for (int f4 = 0; f4 < NF / 4; ++f4) {
        float4 v = *reinterpret_cast<const float4*>(Qs + q * NF + f4 * 4);
        Qreg[f4 * 4 + 0] = v.x; Qreg[f4 * 4 + 1] = v.y;
        Qreg[f4 * 4 + 2] = v.z; Qreg[f4 * 4 + 3] = v.w;
    }

    float m = -INFINITY, l = 0.f;
    float acc[CDS];
#pragma unroll
    for (int c = 0; c < CDS; ++c) acc[c] = 0.f;

    for (int n = jn; n < NPIX; n += 32) {
        // sim[q, n]
        const float* kp = Kt + n * NF;
        float s = 0.f;
#pragma unroll
        for (int f4 = 0; f4 < NF / 4; ++f4) {
            float4 kv = *reinterpret_cast<const float4*>(kp + f4 * 4);
            s = fmaf(Qreg[f4 * 4 + 0], kv.x, s);
            s = fmaf(Qreg[f4 * 4 + 1], kv.y, s);
            s = fmaf(Qreg[f4 * 4 + 2], kv.z, s);
            s = fmaf(Qreg[f4 * 4 + 3], kv.w, s);
        }
        // online softmax (per-lane independent)
        if (s > m) {
            float sc = __expf(m - s);   // exp(-inf)=0 on first hit
            l *= sc;
#pragma unroll
            for (int c = 0; c < CDS; ++c) acc[c] *= sc;
            m = s;
        }
        float w = __expf(s - m);
        l += w;
        const float* vp = Vt + n * CDS;
#pragma unroll
        for (int c4 = 0; c4 < CDS / 4; ++c4) {
            float4 vv = *reinterpret_cast<const float4*>(vp + c4 * 4);
            acc[c4 * 4 + 0] = fmaf(w, vv.x, acc[c4 * 4 + 0]);
            acc[c4 * 4 + 1] = fmaf(w, vv.y, acc[c4 * 4 + 1]);
            acc[c4 * 4 + 2] = fmaf(w, vv.z, acc[c4 * 4 + 2]);
            acc[c4 * 4 + 3] = fmaf(w, vv.w, acc[c4 * 4 + 3]);
        }
    }

    // butterfly merge of 32 per-lane softmax states (within each 32-lane group)
#pragma unroll
    for (int st = 16; st >= 1; st >>= 1) {
        float m2 = __shfl_xor(m, st);
        float l2 = __shfl_xor(l, st);
        float M  = fmaxf(m, m2);
        float s1 = __expf(m - M);
        float s2 = __expf(m2 - M);
        l = l * s1 + l2 * s2;
#pragma unroll
        for (int c = 0; c < CDS; ++c) {
            float a2 = __shfl_xor(acc[c], st);
            acc[c] = acc[c] * s1 + a2 * s2;
        }
        m = M;
    }

    if (jn == 0) {
        float rl = 1.f / l;
#pragma unroll
        for (int c = 0; c < CDS; ++c)
            out[c * NPIX + q] = acc[c] * rl;
    }
}

// ---------------------------------------------------------------------------
extern "C" void kernel_launch(void* const* d_in, const int* in_sizes, int n_in,
                              void* d_out, int out_size, void* d_ws, size_t ws_size,
                              hipStream_t stream) {
    const float* X       = (const float*)d_in[0];   // (64,80,80)
    const float* WQ_task = (const float*)d_in[1];   // (8,64)
    const float* BQ_task = (const float*)d_in[2];   // (8,64)
    const float* WK_task = (const float*)d_in[3];   // (64)
    const float* BK_task = (const float*)d_in[4];   // (64)
    const float* WV_task = (const float*)d_in[5];   // (32)
    const float* BV_task = (const float*)d_in[6];   // (32)
    const float* WQ_tm1  = (const float*)d_in[7];   // (8,64)
    const float* WQ_x    = (const float*)d_in[8];   // (64)
    const float* BQ      = (const float*)d_in[9];   // (8,64)
    const float* WK_x    = (const float*)d_in[10];  // (64)
    const float* BK      = (const float*)d_in[11];  // (64)
    const float* prev_Q  = (const float*)d_in[12];  // (8,64,80,80)
    const float* Vconv_w = (const float*)d_in[13];  // (32,64,3,3)
    const float* Vconv_b = (const float*)d_in[14];  // (32)

    float* ws = (float*)d_ws;
    float* Qs = ws;                       // 6400*64 floats
    float* Kt = ws + NPIX * NF;           // 6400*64 floats
    float* Vt = ws + 2 * NPIX * NF;       // 6400*32 floats  (total 4,096,000 B)

    prep_qk<<<(NF * NPIX + 255) / 256, 256, 0, stream>>>(
        X, WQ_task, BQ_task, WK_task, BK_task, WQ_tm1, WQ_x, BQ, WK_x, BK,
        prev_Q, Qs, Kt);
    prep_v<<<(CDS * NPIX + 255) / 256, 256, 0, stream>>>(
        X, Vconv_w, Vconv_b, WV_task, BV_task, Vt);
    attn_fused<<<NPIX / 8, 256, 0, stream>>>(Qs, Kt, Vt, (float*)d_out);
}

// Round 2
// 164.758 us; speedup vs baseline: 13.1933x; 13.1933x over previous
//
#include <hip/hip_runtime.h>
#include <math.h>

#define NPIX  6400
#define NF    64
#define NH    8
#define CDS   32
#define KSPLIT 4
#define KEYS_PER_SPLIT 1600   // 6400/4
#define TILES_PER_SPLIT 25    // 1600/64

typedef __attribute__((ext_vector_type(8))) short s8v;   // 8 bf16
typedef __attribute__((ext_vector_type(4))) float f4v;

__device__ __forceinline__ unsigned short f2bf(float f) {
    unsigned int u = __float_as_uint(f);
    unsigned int r = (u + 0x7fffu + ((u >> 16) & 1u)) >> 16;   // RNE
    return (unsigned short)r;
}
__device__ __forceinline__ float bf2f(unsigned short h) {
    return __uint_as_float(((unsigned int)h) << 16);
}

// DPP row_ror reductions within aligned 16-lane rows (VALU pipe, no LDS)
#define ROWRED16_MAX(x) { \
    int _t; \
    _t = __builtin_amdgcn_update_dpp(0, __float_as_int(x), 0x128, 0xf, 0xf, 0); x = fmaxf(x, __int_as_float(_t)); \
    _t = __builtin_amdgcn_update_dpp(0, __float_as_int(x), 0x124, 0xf, 0xf, 0); x = fmaxf(x, __int_as_float(_t)); \
    _t = __builtin_amdgcn_update_dpp(0, __float_as_int(x), 0x122, 0xf, 0xf, 0); x = fmaxf(x, __int_as_float(_t)); \
    _t = __builtin_amdgcn_update_dpp(0, __float_as_int(x), 0x121, 0xf, 0xf, 0); x = fmaxf(x, __int_as_float(_t)); }
#define ROWRED16_SUM(x) { \
    int _t; \
    _t = __builtin_amdgcn_update_dpp(0, __float_as_int(x), 0x128, 0xf, 0xf, 0); x += __int_as_float(_t); \
    _t = __builtin_amdgcn_update_dpp(0, __float_as_int(x), 0x124, 0xf, 0xf, 0); x += __int_as_float(_t); \
    _t = __builtin_amdgcn_update_dpp(0, __float_as_int(x), 0x122, 0xf, 0xf, 0); x += __int_as_float(_t); \
    _t = __builtin_amdgcn_update_dpp(0, __float_as_int(x), 0x121, 0xf, 0xf, 0); x += __int_as_float(_t); }

// ---------------------------------------------------------------------------
// prep_k: K = WK_task*(WK_x*X + BK) + BK_task, split into hi/lo bf16,
// stored row-major [pixel][64f].  idx = fc*6400 + p (p fast => coalesced).
// ---------------------------------------------------------------------------
__global__ __launch_bounds__(256)
void prep_k(const float* __restrict__ X,
            const float* __restrict__ WK_task, const float* __restrict__ BK_task,
            const float* __restrict__ WK_x, const float* __restrict__ BK,
            unsigned short* __restrict__ KhG, unsigned short* __restrict__ KlG) {
    int idx = blockIdx.x * 256 + threadIdx.x;           // < 51200
    int p = idx % NPIX, fc = idx / NPIX;                // fc in 0..7
    s8v hv, lv;
#pragma unroll
    for (int j = 0; j < 8; ++j) {
        int f = fc * 8 + j;
        float x = X[f * NPIX + p];
        float kv = WK_task[f] * (WK_x[f] * x + BK[f]) + BK_task[f];
        unsigned short hb = f2bf(kv);
        hv[j] = (short)hb;
        lv[j] = (short)f2bf(kv - bf2f(hb));
    }
    *(s8v*)(KhG + p * 64 + fc * 8) = hv;
    *(s8v*)(KlG + p * 64 + fc * 8) = lv;
}

// ---------------------------------------------------------------------------
// prep_v: V = WV_task*(conv3x3(X)+b) + BV_task, bf16, stored [c][pixel]
// (c-major so the attention kernel can stage V-tiles per channel row).
// Each thread computes 4 channels for one pixel (X reuse x4).
// ---------------------------------------------------------------------------
__global__ __launch_bounds__(256)
void prep_v(const float* __restrict__ X, const float* __restrict__ Wc,
            const float* __restrict__ bc, const float* __restrict__ WV_task,
            const float* __restrict__ BV_task, unsigned short* __restrict__ VG) {
    int idx = blockIdx.x * 256 + threadIdx.x;           // < 51200
    int p = idx % NPIX, cg = idx / NPIX;                // cg in 0..7
    int x0 = p / 80, y0 = p % 80;
    float acc[4] = {0.f, 0.f, 0.f, 0.f};
    for (int dx = -1; dx <= 1; ++dx) {
        int xx = x0 + dx; if (xx < 0 || xx >= 80) continue;
        for (int dy = -1; dy <= 1; ++dy) {
            int yy = y0 + dy; if (yy < 0 || yy >= 80) continue;
            int pos = (dx + 1) * 3 + (dy + 1);
            const float* xp = X + xx * 80 + yy;
#pragma unroll 16
            for (int i = 0; i < 64; ++i) {
                float xv = xp[i * NPIX];
#pragma unroll
                for (int cc = 0; cc < 4; ++cc)
                    acc[cc] = fmaf(xv, Wc[(cg * 4 + cc) * 576 + i * 9 + pos], acc[cc]);
            }
        }
    }
#pragma unroll
    for (int cc = 0; cc < 4; ++cc) {
        int c = cg * 4 + cc;
        VG[c * NPIX + p] = f2bf(WV_task[c] * (acc[cc] + bc[c]) + BV_task[c]);
    }
}

// ---------------------------------------------------------------------------
// attn_mfma: flash attention with bf16 hi/lo split MFMA.
// grid = 200 q-tiles(32q) x 4 key-splits = 800 blocks, 256 threads (4 waves).
// wave w: q-subtile qs=w>>1 (16 q), key-half kh=w&1 (32 of 64 staged keys).
// Per K-tile(64 keys): stage Kh/Kl [64][64]bf16 (XOR-swizzled) + V [32c][64k].
// QK^T: D[q=4g+r][key=li] via mfma_f32_16x16x32_bf16 (3 products hi/lo).
// Online softmax per q-row with DPP reductions; P -> per-wave LDS -> A-frag;
// PV: acc[q][c] += P(16x32) * V(32x16) per c-tile.
// End: in-block merge of the 2 key-half waves, write 4-way global partials.
// ---------------------------------------------------------------------------
__global__ __launch_bounds__(256)
void attn_mfma(const float* __restrict__ X, const float* __restrict__ prevQ,
               const float* __restrict__ WQ_task, const float* __restrict__ BQ_task,
               const float* __restrict__ WQ_tm1, const float* __restrict__ WQ_x,
               const float* __restrict__ BQ,
               const unsigned short* __restrict__ KhG,
               const unsigned short* __restrict__ KlG,
               const unsigned short* __restrict__ VG,
               float* __restrict__ PmG, float* __restrict__ PlG,
               unsigned short* __restrict__ PaccG) {
    __shared__ __align__(16) char lds[25600];
    // 0..8191: Kh tile [64][64]bf16 swizzled; 8192..16383: Kl; 16384..20479: V [32][64]
    // 20480..25599: per-wave P [16][40]bf16 (80B rows)

    const int tid = threadIdx.x;
    const int w = tid >> 6, l = tid & 63;
    const int g = l >> 4, li = l & 15;
    const int qt = blockIdx.x >> 2, ks4 = blockIdx.x & 3;
    const int qs = w >> 1, kh = w & 1;
    const int qbase = qt * 32 + qs * 16;
    const int kbase = ks4 * KEYS_PER_SPLIT;

    // ---- Q fragments (hi/lo bf16), computed from raw inputs ----
    s8v qh[2], ql[2];
    {
        int q = qbase + li;
#pragma unroll
        for (int kc = 0; kc < 2; ++kc) {
#pragma unroll
            for (int j = 0; j < 8; ++j) {
                int f = kc * 32 + g * 8 + j;
                float x = X[f * NPIX + q];
                float a = 0.f;
#pragma unroll
                for (int h = 0; h < NH; ++h) {
                    int hf = h * 64 + f;
                    float inner = WQ_tm1[hf] * prevQ[hf * NPIX + q] + WQ_x[f] * x + BQ[hf];
                    a += WQ_task[hf] * inner + BQ_task[hf];
                }
                unsigned short hb = f2bf(a);
                qh[kc][j] = (short)hb;
                ql[kc][j] = (short)f2bf(a - bf2f(hb));
            }
        }
    }

    f4v acc0 = {0.f, 0.f, 0.f, 0.f}, acc1 = {0.f, 0.f, 0.f, 0.f};
    float m[4] = {-INFINITY, -INFINITY, -INFINITY, -INFINITY};
    float lsum[4] = {0.f, 0.f, 0.f, 0.f};

    char* pldsw = lds + 20480 + w * 1280;   // this wave's P region

    for (int t = 0; t < TILES_PER_SPLIT; ++t) {
        // issue global loads for this tile (16B each)
        long kgo = (long)(kbase + t * 64) * 64;
        s8v rkh0 = *(const s8v*)(KhG + kgo + (0 * 256 + tid) * 8);
        s8v rkh1 = *(const s8v*)(KhG + kgo + (1 * 256 + tid) * 8);
        s8v rkl0 = *(const s8v*)(KlG + kgo + (0 * 256 + tid) * 8);
        s8v rkl1 = *(const s8v*)(KlG + kgo + (1 * 256 + tid) * 8);
        int vc = tid >> 3, vwi = (tid & 7) * 16;         // V: c-row, in-row byte
        s8v rv = *(const s8v*)(VG + vc * NPIX + kbase + t * 64 + (vwi >> 1));

        __syncthreads();   // previous tile's consumers done
        {
            int o0 = tid * 16, o1 = 4096 + tid * 16;
            int r0 = o0 >> 7, c0 = o0 & 127, r1 = o1 >> 7, c1 = o1 & 127;
            *(s8v*)(lds + r0 * 128 + (c0 ^ ((r0 & 7) << 4))) = rkh0;
            *(s8v*)(lds + r1 * 128 + (c1 ^ ((r1 & 7) << 4))) = rkh1;
            *(s8v*)(lds + 8192 + r0 * 128 + (c0 ^ ((r0 & 7) << 4))) = rkl0;
            *(s8v*)(lds + 8192 + r1 * 128 + (c1 ^ ((r1 & 7) << 4))) = rkl1;
            *(s8v*)(lds + 16384 + vc * 128 + (vwi ^ ((vc & 3) << 4))) = rv;
        }
        __syncthreads();   // tile staged

        // ---- QK^T: two 16-key subtiles for this wave's 32 keys ----
        f4v s[2];
#pragma unroll
        for (int sub = 0; sub < 2; ++sub) {
            f4v sa = {0.f, 0.f, 0.f, 0.f};
            int key = kh * 32 + sub * 16 + li;
            int swz = (key & 7) << 4;
#pragma unroll
            for (int kc = 0; kc < 2; ++kc) {
                int coff = (g * 16 + kc * 64) ^ swz;
                s8v kf  = *(const s8v*)(lds + key * 128 + coff);
                s8v kfl = *(const s8v*)(lds + 8192 + key * 128 + coff);
                sa = __builtin_amdgcn_mfma_f32_16x16x32_bf16(qh[kc], kf,  sa, 0, 0, 0);
                sa = __builtin_amdgcn_mfma_f32_16x16x32_bf16(qh[kc], kfl, sa, 0, 0, 0);
                sa = __builtin_amdgcn_mfma_f32_16x16x32_bf16(ql[kc], kf,  sa, 0, 0, 0);
            }
            s[sub] = sa;
        }

        // ---- online softmax per q-row (row = 4g+r), DPP reductions ----
#pragma unroll
        for (int r = 0; r < 4; ++r) {
            float s0 = s[0][r], s1 = s[1][r];
            float mx = fmaxf(s0, s1);
            ROWRED16_MAX(mx);
            float mn = fmaxf(m[r], mx);
            float p0 = __expf(s0 - mn), p1 = __expf(s1 - mn);
            float rs = p0 + p1;
            ROWRED16_SUM(rs);
            float sc = __expf(m[r] - mn);
            lsum[r] = lsum[r] * sc + rs;
            m[r] = mn;
            acc0[r] *= sc; acc1[r] *= sc;
            *(unsigned short*)(pldsw + (4 * g + r) * 80 + li * 2)        = f2bf(p0);
            *(unsigned short*)(pldsw + (4 * g + r) * 80 + 32 + li * 2)   = f2bf(p1);
        }

        // ---- PV: A = P[16q][32k] (reload as A-frag), B = V[32k][16c] ----
        s8v pf = *(const s8v*)(pldsw + li * 80 + g * 16);
        {
            int c0 = li, c1 = 16 + li;
            int k0 = kh * 64 + g * 16;
            s8v v0 = *(const s8v*)(lds + 16384 + c0 * 128 + (k0 ^ ((c0 & 3) << 4)));
            s8v v1 = *(const s8v*)(lds + 16384 + c1 * 128 + (k0 ^ ((c1 & 3) << 4)));
            acc0 = __builtin_amdgcn_mfma_f32_16x16x32_bf16(pf, v0, acc0, 0, 0, 0);
            acc1 = __builtin_amdgcn_mfma_f32_16x16x32_bf16(pf, v1, acc1, 0, 0, 0);
        }
    }

    // ---- in-block merge of key-half wave pairs, write global partials ----
    __syncthreads();
    float* macc = (float*)lds;           // [4 waves][16 q][32 c]
    float* mmm  = (float*)(lds + 8192);  // [4][16]
    float* mll  = (float*)(lds + 8448);  // [4][16]
#pragma unroll
    for (int r = 0; r < 4; ++r) {
        macc[w * 512 + (4 * g + r) * 32 + li]      = acc0[r];
        macc[w * 512 + (4 * g + r) * 32 + 16 + li] = acc1[r];
        if (li == 0) { mmm[w * 16 + 4 * g + r] = m[r]; mll[w * 16 + 4 * g + r] = lsum[r]; }
    }
    __syncthreads();
#pragma unroll
    for (int rep = 0; rep < 4; ++rep) {
        int idx = rep * 256 + tid;                  // < 1024 = 2qs*16q*32c
        int qs2 = idx >> 9, qq = (idx >> 5) & 15, c = idx & 31;
        int w0 = qs2 * 2, w1 = w0 + 1;
        float m0 = mmm[w0 * 16 + qq], m1 = mmm[w1 * 16 + qq];
        float M = fmaxf(m0, m1);
        float e0 = __expf(m0 - M), e1 = __expf(m1 - M);
        float L = mll[w0 * 16 + qq] * e0 + mll[w1 * 16 + qq] * e1;
        float A = macc[w0 * 512 + qq * 32 + c] * e0 + macc[w1 * 512 + qq * 32 + c] * e1;
        int qg = qt * 32 + qs2 * 16 + qq;
        PaccG[ks4 * 204800 + qg * 32 + c] = f2bf(A);
        if (c == 0) { PmG[ks4 * NPIX + qg] = M; PlG[ks4 * NPIX + qg] = L; }
    }
}

// ---------------------------------------------------------------------------
// merge_out: combine the 4 key-split partials -> out[c][q]
// ---------------------------------------------------------------------------
__global__ __launch_bounds__(256)
void merge_out(const float* __restrict__ Pm, const float* __restrict__ Pl,
               const unsigned short* __restrict__ Pacc, float* __restrict__ out) {
    int idx = blockIdx.x * 256 + threadIdx.x;       // < 204800
    int q = idx >> 5, c = idx & 31;
    float m0 = Pm[q], m1 = Pm[NPIX + q], m2 = Pm[2 * NPIX + q], m3 = Pm[3 * NPIX + q];
    float M = fmaxf(fmaxf(m0, m1), fmaxf(m2, m3));
    float e0 = __expf(m0 - M), e1 = __expf(m1 - M), e2 = __expf(m2 - M), e3 = __expf(m3 - M);
    float den = Pl[q] * e0 + Pl[NPIX + q] * e1 + Pl[2 * NPIX + q] * e2 + Pl[3 * NPIX + q] * e3;
    float num = bf2f(Pacc[q * 32 + c]) * e0 + bf2f(Pacc[204800 + q * 32 + c]) * e1
              + bf2f(Pacc[409600 + q * 32 + c]) * e2 + bf2f(Pacc[614400 + q * 32 + c]) * e3;
    out[c * NPIX + q] = num / den;
}

// ---------------------------------------------------------------------------
extern "C" void kernel_launch(void* const* d_in, const int* in_sizes, int n_in,
                              void* d_out, int out_size, void* d_ws, size_t ws_size,
                              hipStream_t stream) {
    const float* X       = (const float*)d_in[0];
    const float* WQ_task = (const float*)d_in[1];
    const float* BQ_task = (const float*)d_in[2];
    const float* WK_task = (const float*)d_in[3];
    const float* BK_task = (const float*)d_in[4];
    const float* WV_task = (const float*)d_in[5];
    const float* BV_task = (const float*)d_in[6];
    const float* WQ_tm1  = (const float*)d_in[7];
    const float* WQ_x    = (const float*)d_in[8];
    const float* BQ      = (const float*)d_in[9];
    const float* WK_x    = (const float*)d_in[10];
    const float* BK      = (const float*)d_in[11];
    const float* prev_Q  = (const float*)d_in[12];
    const float* Vconv_w = (const float*)d_in[13];
    const float* Vconv_b = (const float*)d_in[14];

    char* wsb = (char*)d_ws;
    unsigned short* KhG  = (unsigned short*)(wsb + 0);        //  819200 B
    unsigned short* KlG  = (unsigned short*)(wsb + 819200);   //  819200 B
    unsigned short* VG   = (unsigned short*)(wsb + 1638400);  //  409600 B
    float*          PmG  = (float*)(wsb + 2048000);           //  102400 B
    float*          PlG  = (float*)(wsb + 2150400);           //  102400 B
    unsigned short* PaccG= (unsigned short*)(wsb + 2252800);  // 1638400 B -> 3891200 total

    prep_k<<<200, 256, 0, stream>>>(X, WK_task, BK_task, WK_x, BK, KhG, KlG);
    prep_v<<<200, 256, 0, stream>>>(X, Vconv_w, Vconv_b, WV_task, BV_task, VG);
    attn_mfma<<<800, 256, 0, stream>>>(X, prev_Q, WQ_task, BQ_task, WQ_tm1, WQ_x, BQ,
                                       KhG, KlG, VG, PmG, PlG, PaccG);
    merge_out<<<800, 256, 0, stream>>>(PmG, PlG, PaccG, (float*)d_out);
}

// Round 3
// 96.522 us; speedup vs baseline: 22.5204x; 1.7070x over previous
//
#include <hip/hip_runtime.h>
#include <math.h>

#define NPIX  6400
#define NF    64
#define NH    8
#define CDS   32
#define KSPLIT 4
#define KEYS_PER_SPLIT 1600   // 6400/4
#define TILES_PER_SPLIT 25    // 1600/64

typedef __attribute__((ext_vector_type(8))) short s8v;   // 8 bf16
typedef __attribute__((ext_vector_type(4))) float f4v;

__device__ __forceinline__ unsigned short f2bf(float f) {
    unsigned int u = __float_as_uint(f);
    unsigned int r = (u + 0x7fffu + ((u >> 16) & 1u)) >> 16;   // RNE
    return (unsigned short)r;
}
__device__ __forceinline__ float bf2f(unsigned short h) {
    return __uint_as_float(((unsigned int)h) << 16);
}

// DPP row_ror reductions within aligned 16-lane rows (VALU pipe, no LDS)
#define ROWRED16_MAX(x) { \
    int _t; \
    _t = __builtin_amdgcn_update_dpp(0, __float_as_int(x), 0x128, 0xf, 0xf, 0); x = fmaxf(x, __int_as_float(_t)); \
    _t = __builtin_amdgcn_update_dpp(0, __float_as_int(x), 0x124, 0xf, 0xf, 0); x = fmaxf(x, __int_as_float(_t)); \
    _t = __builtin_amdgcn_update_dpp(0, __float_as_int(x), 0x122, 0xf, 0xf, 0); x = fmaxf(x, __int_as_float(_t)); \
    _t = __builtin_amdgcn_update_dpp(0, __float_as_int(x), 0x121, 0xf, 0xf, 0); x = fmaxf(x, __int_as_float(_t)); }
#define ROWRED16_SUM(x) { \
    int _t; \
    _t = __builtin_amdgcn_update_dpp(0, __float_as_int(x), 0x128, 0xf, 0xf, 0); x += __int_as_float(_t); \
    _t = __builtin_amdgcn_update_dpp(0, __float_as_int(x), 0x124, 0xf, 0xf, 0); x += __int_as_float(_t); \
    _t = __builtin_amdgcn_update_dpp(0, __float_as_int(x), 0x122, 0xf, 0xf, 0); x += __int_as_float(_t); \
    _t = __builtin_amdgcn_update_dpp(0, __float_as_int(x), 0x121, 0xf, 0xf, 0); x += __int_as_float(_t); }

// ---------------------------------------------------------------------------
// prep_qs: Qs (head-summed Q) hi/lo bf16, stored [pixel][64f].
// grid: blockIdx = fg*25 + pb  (fg = feature-group of 8, pb = 256-pixel chunk)
// prevQ read fully coalesced, exactly once.
// ---------------------------------------------------------------------------
__global__ __launch_bounds__(256)
void prep_qs(const float* __restrict__ X, const float* __restrict__ prevQ,
             const float* __restrict__ WQ_task, const float* __restrict__ BQ_task,
             const float* __restrict__ WQ_tm1, const float* __restrict__ WQ_x,
             const float* __restrict__ BQ,
             unsigned short* __restrict__ QhG, unsigned short* __restrict__ QlG) {
    int fg = blockIdx.x / 25;
    int p  = (blockIdx.x % 25) * 256 + threadIdx.x;
    s8v hv, lv;
#pragma unroll
    for (int j = 0; j < 8; ++j) {
        int f = fg * 8 + j;
        float x = X[f * NPIX + p];
        float wqx_x = WQ_x[f] * x;
        float a = 0.f;
#pragma unroll
        for (int h = 0; h < NH; ++h) {
            int hf = h * 64 + f;
            float inner = WQ_tm1[hf] * prevQ[hf * NPIX + p] + wqx_x + BQ[hf];
            a += WQ_task[hf] * inner + BQ_task[hf];
        }
        unsigned short hb = f2bf(a);
        hv[j] = (short)hb;
        lv[j] = (short)f2bf(a - bf2f(hb));
    }
    *(s8v*)(QhG + p * 64 + fg * 8) = hv;
    *(s8v*)(QlG + p * 64 + fg * 8) = lv;
}

// ---------------------------------------------------------------------------
// prep_k: K hi/lo bf16, stored [pixel][64f].  Same grid decomposition.
// ---------------------------------------------------------------------------
__global__ __launch_bounds__(256)
void prep_k(const float* __restrict__ X,
            const float* __restrict__ WK_task, const float* __restrict__ BK_task,
            const float* __restrict__ WK_x, const float* __restrict__ BK,
            unsigned short* __restrict__ KhG, unsigned short* __restrict__ KlG) {
    int fg = blockIdx.x / 25;
    int p  = (blockIdx.x % 25) * 256 + threadIdx.x;
    s8v hv, lv;
#pragma unroll
    for (int j = 0; j < 8; ++j) {
        int f = fg * 8 + j;
        float x = X[f * NPIX + p];
        float kv = WK_task[f] * (WK_x[f] * x + BK[f]) + BK_task[f];
        unsigned short hb = f2bf(kv);
        hv[j] = (short)hb;
        lv[j] = (short)f2bf(kv - bf2f(hb));
    }
    *(s8v*)(KhG + p * 64 + fg * 8) = hv;
    *(s8v*)(KlG + p * 64 + fg * 8) = lv;
}

// ---------------------------------------------------------------------------
// prep_v: V = WV_task*(conv3x3(X)+b) + BV_task, bf16, stored [c][pixel].
// cg is SCALAR (from blockIdx) so weight loads become hoisted s_loads.
// ---------------------------------------------------------------------------
__global__ __launch_bounds__(256)
void prep_v(const float* __restrict__ X, const float* __restrict__ Wc,
            const float* __restrict__ bc, const float* __restrict__ WV_task,
            const float* __restrict__ BV_task, unsigned short* __restrict__ VG) {
    int cg = blockIdx.x / 25;                       // 0..7 (scalar)
    int p  = (blockIdx.x % 25) * 256 + threadIdx.x;
    int x0 = p / 80, y0 = p % 80;
    float acc[4] = {0.f, 0.f, 0.f, 0.f};
    for (int dx = -1; dx <= 1; ++dx) {
        int xx = x0 + dx; if (xx < 0 || xx >= 80) continue;
        for (int dy = -1; dy <= 1; ++dy) {
            int yy = y0 + dy; if (yy < 0 || yy >= 80) continue;
            const float* wp = Wc + (cg * 4) * 576 + (dx + 1) * 3 + (dy + 1);
            const float* xp = X + xx * 80 + yy;
#pragma unroll 16
            for (int i = 0; i < 64; ++i) {
                float xv = xp[i * NPIX];
#pragma unroll
                for (int cc = 0; cc < 4; ++cc)
                    acc[cc] = fmaf(xv, wp[cc * 576 + i * 9], acc[cc]);
            }
        }
    }
#pragma unroll
    for (int cc = 0; cc < 4; ++cc) {
        int c = cg * 4 + cc;
        VG[c * NPIX + p] = f2bf(WV_task[c] * (acc[cc] + bc[c]) + BV_task[c]);
    }
}

// ---------------------------------------------------------------------------
// attn_mfma: flash attention, bf16 hi/lo split MFMA.
// grid = 200 q-tiles(32q) x 4 key-splits.  4 waves = 2 q-subtiles x 2 key-halves.
// Key order inside a wave is interleaved (key = kh*32 + 2*li + sub) so the two
// P values per (row, lane) pack into one u32 LDS store.
// Softmax: DPP row-max; rescale only when max grows (__any); per-lane lsum
// deferred to one end-of-loop DPP-sum; P packed by truncation.
// ---------------------------------------------------------------------------
__global__ __launch_bounds__(256)
void attn_mfma(const unsigned short* __restrict__ QhG,
               const unsigned short* __restrict__ QlG,
               const unsigned short* __restrict__ KhG,
               const unsigned short* __restrict__ KlG,
               const unsigned short* __restrict__ VG,
               float* __restrict__ PmG, float* __restrict__ PlG,
               unsigned short* __restrict__ PaccG) {
    __shared__ __align__(16) char lds[25600];
    // 0..8191 Kh [64][64]bf16 swz; 8192..16383 Kl; 16384..20479 V [32][64];
    // 20480..25599 per-wave P [16 rows][80 B]

    const int tid = threadIdx.x;
    const int w = tid >> 6, l = tid & 63;
    const int g = l >> 4, li = l & 15;
    const int qt = blockIdx.x >> 2, ks4 = blockIdx.x & 3;
    const int qs = w >> 1, kh = w & 1;
    const int qbase = qt * 32 + qs * 16;
    const int kbase = ks4 * KEYS_PER_SPLIT;

    // ---- Q fragments from precomputed global (4 x 16B) ----
    s8v qh[2], ql[2];
    {
        const unsigned short* qb = QhG + (qbase + li) * 64 + g * 8;
        qh[0] = *(const s8v*)(qb);
        qh[1] = *(const s8v*)(qb + 32);
        const unsigned short* qb2 = QlG + (qbase + li) * 64 + g * 8;
        ql[0] = *(const s8v*)(qb2);
        ql[1] = *(const s8v*)(qb2 + 32);
    }

    // ---- loop-invariant LDS addresses ----
    int kaddr[2][2];
#pragma unroll
    for (int sub = 0; sub < 2; ++sub) {
        int key = kh * 32 + li * 2 + sub;
        int swz = (key & 7) << 4;
#pragma unroll
        for (int kc = 0; kc < 2; ++kc)
            kaddr[sub][kc] = key * 128 + ((g * 16 + kc * 64) ^ swz);
    }
    const int vaddr0 = 16384 + li * 128 + ((kh * 64 + g * 16) ^ ((li & 3) << 4));
    const int vaddr1 = 16384 + (li + 16) * 128 + ((kh * 64 + g * 16) ^ (((li + 16) & 3) << 4));
    char* pldsw = lds + 20480 + w * 1280;
    const int pw_store = (4 * g) * 80 + li * 4;
    const int pr_addr  = li * 80 + g * 16;
    const int o0 = tid * 16, o1 = 4096 + tid * 16;
    const int r0 = o0 >> 7, c0 = o0 & 127, r1 = o1 >> 7, c1 = o1 & 127;
    const int st_k0 = r0 * 128 + (c0 ^ ((r0 & 7) << 4));
    const int st_k1 = r1 * 128 + (c1 ^ ((r1 & 7) << 4));
    const int vc = tid >> 3, vwi = (tid & 7) * 16;
    const int st_v = 16384 + vc * 128 + (vwi ^ ((vc & 3) << 4));
    const unsigned short* kgp = KhG + (long)kbase * 64 + tid * 8;
    const unsigned short* klp = KlG + (long)kbase * 64 + tid * 8;
    const unsigned short* vgp = VG + vc * NPIX + kbase + (vwi >> 1);

    f4v acc0 = {0.f, 0.f, 0.f, 0.f}, acc1 = {0.f, 0.f, 0.f, 0.f};
    float m[4]    = {-INFINITY, -INFINITY, -INFINITY, -INFINITY};
    float lsum[4] = {0.f, 0.f, 0.f, 0.f};

    for (int t = 0; t < TILES_PER_SPLIT; ++t) {
        s8v rkh0 = *(const s8v*)(kgp);
        s8v rkh1 = *(const s8v*)(kgp + 2048);
        s8v rkl0 = *(const s8v*)(klp);
        s8v rkl1 = *(const s8v*)(klp + 2048);
        s8v rv   = *(const s8v*)(vgp);
        kgp += 4096; klp += 4096; vgp += 64;

        __syncthreads();
        *(s8v*)(lds + st_k0) = rkh0;
        *(s8v*)(lds + st_k1) = rkh1;
        *(s8v*)(lds + 8192 + st_k0) = rkl0;
        *(s8v*)(lds + 8192 + st_k1) = rkl1;
        *(s8v*)(lds + st_v) = rv;
        __syncthreads();

        // ---- QK^T (interleaved key cols: s0 -> key 2li, s1 -> key 2li+1) ----
        f4v s0 = {0.f, 0.f, 0.f, 0.f}, s1 = {0.f, 0.f, 0.f, 0.f};
#pragma unroll
        for (int kc = 0; kc < 2; ++kc) {
            s8v kf0 = *(const s8v*)(lds + kaddr[0][kc]);
            s8v kg0 = *(const s8v*)(lds + 8192 + kaddr[0][kc]);
            s8v kf1 = *(const s8v*)(lds + kaddr[1][kc]);
            s8v kg1 = *(const s8v*)(lds + 8192 + kaddr[1][kc]);
            s0 = __builtin_amdgcn_mfma_f32_16x16x32_bf16(qh[kc], kf0, s0, 0, 0, 0);
            s0 = __builtin_amdgcn_mfma_f32_16x16x32_bf16(qh[kc], kg0, s0, 0, 0, 0);
            s0 = __builtin_amdgcn_mfma_f32_16x16x32_bf16(ql[kc], kf0, s0, 0, 0, 0);
            s1 = __builtin_amdgcn_mfma_f32_16x16x32_bf16(qh[kc], kf1, s1, 0, 0, 0);
            s1 = __builtin_amdgcn_mfma_f32_16x16x32_bf16(qh[kc], kg1, s1, 0, 0, 0);
            s1 = __builtin_amdgcn_mfma_f32_16x16x32_bf16(ql[kc], kf1, s1, 0, 0, 0);
        }

        // ---- online softmax ----
        float mx[4];
#pragma unroll
        for (int r = 0; r < 4; ++r) {
            float v = fmaxf(s0[r], s1[r]);
            ROWRED16_MAX(v);
            mx[r] = v;
        }
        if (__any((mx[0] > m[0]) | (mx[1] > m[1]) | (mx[2] > m[2]) | (mx[3] > m[3]))) {
#pragma unroll
            for (int r = 0; r < 4; ++r) {
                float mn = fmaxf(m[r], mx[r]);
                float sc = __expf(m[r] - mn);
                lsum[r] *= sc; acc0[r] *= sc; acc1[r] *= sc; m[r] = mn;
            }
        }
#pragma unroll
        for (int r = 0; r < 4; ++r) {
            float p0 = __expf(s0[r] - m[r]);
            float p1 = __expf(s1[r] - m[r]);
            lsum[r] += p0 + p1;
            unsigned pk = (__float_as_uint(p0) >> 16) | (__float_as_uint(p1) & 0xffff0000u);
            *(unsigned*)(pldsw + pw_store + r * 80) = pk;
        }

        // ---- PV ----
        s8v pf = *(const s8v*)(pldsw + pr_addr);
        s8v v0 = *(const s8v*)(lds + vaddr0);
        s8v v1 = *(const s8v*)(lds + vaddr1);
        acc0 = __builtin_amdgcn_mfma_f32_16x16x32_bf16(pf, v0, acc0, 0, 0, 0);
        acc1 = __builtin_amdgcn_mfma_f32_16x16x32_bf16(pf, v1, acc1, 0, 0, 0);
    }

    // ---- finalize per-row l, then in-block merge of key-half wave pairs ----
#pragma unroll
    for (int r = 0; r < 4; ++r) { ROWRED16_SUM(lsum[r]); }

    __syncthreads();
    float* macc = (float*)lds;           // [4 waves][16 q][32 c]
    float* mmm  = (float*)(lds + 8192);  // [4][16]
    float* mll  = (float*)(lds + 8448);  // [4][16]
#pragma unroll
    for (int r = 0; r < 4; ++r) {
        macc[w * 512 + (4 * g + r) * 32 + li]      = acc0[r];
        macc[w * 512 + (4 * g + r) * 32 + 16 + li] = acc1[r];
        if (li == 0) { mmm[w * 16 + 4 * g + r] = m[r]; mll[w * 16 + 4 * g + r] = lsum[r]; }
    }
    __syncthreads();
#pragma unroll
    for (int rep = 0; rep < 4; ++rep) {
        int idx = rep * 256 + tid;                  // < 1024
        int qs2 = idx >> 9, qq = (idx >> 5) & 15, c = idx & 31;
        int w0 = qs2 * 2, w1 = w0 + 1;
        float m0 = mmm[w0 * 16 + qq], m1 = mmm[w1 * 16 + qq];
        float M = fmaxf(m0, m1);
        float e0 = __expf(m0 - M), e1 = __expf(m1 - M);
        float L = mll[w0 * 16 + qq] * e0 + mll[w1 * 16 + qq] * e1;
        float A = macc[w0 * 512 + qq * 32 + c] * e0 + macc[w1 * 512 + qq * 32 + c] * e1;
        int qg = qt * 32 + qs2 * 16 + qq;
        PaccG[ks4 * 204800 + qg * 32 + c] = f2bf(A);
        if (c == 0) { PmG[ks4 * NPIX + qg] = M; PlG[ks4 * NPIX + qg] = L; }
    }
}

// ---------------------------------------------------------------------------
__global__ __launch_bounds__(256)
void merge_out(const float* __restrict__ Pm, const float* __restrict__ Pl,
               const unsigned short* __restrict__ Pacc, float* __restrict__ out) {
    int idx = blockIdx.x * 256 + threadIdx.x;       // < 204800
    int q = idx >> 5, c = idx & 31;
    float m0 = Pm[q], m1 = Pm[NPIX + q], m2 = Pm[2 * NPIX + q], m3 = Pm[3 * NPIX + q];
    float M = fmaxf(fmaxf(m0, m1), fmaxf(m2, m3));
    float e0 = __expf(m0 - M), e1 = __expf(m1 - M), e2 = __expf(m2 - M), e3 = __expf(m3 - M);
    float den = Pl[q] * e0 + Pl[NPIX + q] * e1 + Pl[2 * NPIX + q] * e2 + Pl[3 * NPIX + q] * e3;
    float num = bf2f(Pacc[q * 32 + c]) * e0 + bf2f(Pacc[204800 + q * 32 + c]) * e1
              + bf2f(Pacc[409600 + q * 32 + c]) * e2 + bf2f(Pacc[614400 + q * 32 + c]) * e3;
    out[c * NPIX + q] = num / den;
}

// ---------------------------------------------------------------------------
extern "C" void kernel_launch(void* const* d_in, const int* in_sizes, int n_in,
                              void* d_out, int out_size, void* d_ws, size_t ws_size,
                              hipStream_t stream) {
    const float* X       = (const float*)d_in[0];
    const float* WQ_task = (const float*)d_in[1];
    const float* BQ_task = (const float*)d_in[2];
    const float* WK_task = (const float*)d_in[3];
    const float* BK_task = (const float*)d_in[4];
    const float* WV_task = (const float*)d_in[5];
    const float* BV_task = (const float*)d_in[6];
    const float* WQ_tm1  = (const float*)d_in[7];
    const float* WQ_x    = (const float*)d_in[8];
    const float* BQ      = (const float*)d_in[9];
    const float* WK_x    = (const float*)d_in[10];
    const float* BK      = (const float*)d_in[11];
    const float* prev_Q  = (const float*)d_in[12];
    const float* Vconv_w = (const float*)d_in[13];
    const float* Vconv_b = (const float*)d_in[14];

    char* wsb = (char*)d_ws;
    unsigned short* QhG  = (unsigned short*)(wsb + 0);        //  819200
    unsigned short* QlG  = (unsigned short*)(wsb + 819200);   //  819200
    unsigned short* KhG  = (unsigned short*)(wsb + 1638400);  //  819200
    unsigned short* KlG  = (unsigned short*)(wsb + 2457600);  //  819200
    unsigned short* VG   = (unsigned short*)(wsb + 3276800);  //  409600
    float*          PmG  = (float*)(wsb + 3686400);           //  102400
    float*          PlG  = (float*)(wsb + 3788800);           //  102400
    unsigned short* PaccG= (unsigned short*)(wsb + 3891200);  // 1638400 -> 5529600 total

    prep_qs<<<200, 256, 0, stream>>>(X, prev_Q, WQ_task, BQ_task, WQ_tm1, WQ_x, BQ,
                                     QhG, QlG);
    prep_k<<<200, 256, 0, stream>>>(X, WK_task, BK_task, WK_x, BK, KhG, KlG);
    prep_v<<<200, 256, 0, stream>>>(X, Vconv_w, Vconv_b, WV_task, BV_task, VG);
    attn_mfma<<<800, 256, 0, stream>>>(QhG, QlG, KhG, KlG, VG, PmG, PlG, PaccG);
    merge_out<<<800, 256, 0, stream>>>(PmG, PlG, PaccG, (float*)d_out);
}

// Round 4
// 96.233 us; speedup vs baseline: 22.5880x; 1.0030x over previous
//
#include <hip/hip_runtime.h>
#include <math.h>

#define NPIX  6400
#define NF    64
#define NH    8
#define CDS   32
#define KEYS_PER_SPLIT 1600   // 6400/4
#define TILES_PER_SPLIT 25    // 1600/64

typedef __attribute__((ext_vector_type(8))) short s8v;   // 8 bf16
typedef __attribute__((ext_vector_type(4))) float f4v;

__device__ __forceinline__ unsigned short f2bf(float f) {
    unsigned int u = __float_as_uint(f);
    unsigned int r = (u + 0x7fffu + ((u >> 16) & 1u)) >> 16;   // RNE
    return (unsigned short)r;
}
__device__ __forceinline__ float bf2f(unsigned short h) {
    return __uint_as_float(((unsigned int)h) << 16);
}

// DPP row_ror reductions within aligned 16-lane rows (VALU pipe, no LDS)
#define ROWRED16_MAX(x) { \
    int _t; \
    _t = __builtin_amdgcn_update_dpp(0, __float_as_int(x), 0x128, 0xf, 0xf, 0); x = fmaxf(x, __int_as_float(_t)); \
    _t = __builtin_amdgcn_update_dpp(0, __float_as_int(x), 0x124, 0xf, 0xf, 0); x = fmaxf(x, __int_as_float(_t)); \
    _t = __builtin_amdgcn_update_dpp(0, __float_as_int(x), 0x122, 0xf, 0xf, 0); x = fmaxf(x, __int_as_float(_t)); \
    _t = __builtin_amdgcn_update_dpp(0, __float_as_int(x), 0x121, 0xf, 0xf, 0); x = fmaxf(x, __int_as_float(_t)); }
#define ROWRED16_SUM(x) { \
    int _t; \
    _t = __builtin_amdgcn_update_dpp(0, __float_as_int(x), 0x128, 0xf, 0xf, 0); x += __int_as_float(_t); \
    _t = __builtin_amdgcn_update_dpp(0, __float_as_int(x), 0x124, 0xf, 0xf, 0); x += __int_as_float(_t); \
    _t = __builtin_amdgcn_update_dpp(0, __float_as_int(x), 0x122, 0xf, 0xf, 0); x += __int_as_float(_t); \
    _t = __builtin_amdgcn_update_dpp(0, __float_as_int(x), 0x121, 0xf, 0xf, 0); x += __int_as_float(_t); }

// ---------------------------------------------------------------------------
// prep_qk: fused Qs (head-summed) and K, hi/lo bf16, stored [pixel][64f].
// grid = 16 feature-groups(4f) x 25 pixel-chunks = 400 blocks.
// ---------------------------------------------------------------------------
__global__ __launch_bounds__(256)
void prep_qk(const float* __restrict__ X, const float* __restrict__ prevQ,
             const float* __restrict__ WQ_task, const float* __restrict__ BQ_task,
             const float* __restrict__ WQ_tm1, const float* __restrict__ WQ_x,
             const float* __restrict__ BQ,
             const float* __restrict__ WK_task, const float* __restrict__ BK_task,
             const float* __restrict__ WK_x, const float* __restrict__ BK,
             unsigned short* __restrict__ QhG, unsigned short* __restrict__ QlG,
             unsigned short* __restrict__ KhG, unsigned short* __restrict__ KlG) {
    int fg = blockIdx.x / 25;                       // 0..15
    int p  = (blockIdx.x % 25) * 256 + threadIdx.x;
    unsigned short qh_[4], ql_[4], kh_[4], kl_[4];
#pragma unroll
    for (int j = 0; j < 4; ++j) {
        int f = fg * 4 + j;
        float x = X[f * NPIX + p];
        // K
        float kv = WK_task[f] * (WK_x[f] * x + BK[f]) + BK_task[f];
        unsigned short khb = f2bf(kv);
        kh_[j] = khb;
        kl_[j] = f2bf(kv - bf2f(khb));
        // Q (head-summed)
        float wqx_x = WQ_x[f] * x;
        float a = 0.f;
#pragma unroll
        for (int h = 0; h < NH; ++h) {
            int hf = h * 64 + f;
            float inner = WQ_tm1[hf] * prevQ[hf * NPIX + p] + wqx_x + BQ[hf];
            a += WQ_task[hf] * inner + BQ_task[hf];
        }
        unsigned short qhb = f2bf(a);
        qh_[j] = qhb;
        ql_[j] = f2bf(a - bf2f(qhb));
    }
    *(ushort4*)(QhG + p * 64 + fg * 4) = *(ushort4*)qh_;
    *(ushort4*)(QlG + p * 64 + fg * 4) = *(ushort4*)ql_;
    *(ushort4*)(KhG + p * 64 + fg * 4) = *(ushort4*)kh_;
    *(ushort4*)(KlG + p * 64 + fg * 4) = *(ushort4*)kl_;
}

// ---------------------------------------------------------------------------
// prep_v: V = WV_task*(conv3x3(X)+b) + BV_task, bf16, stored [c][pixel].
// grid = 32 channels x 25 pixel-chunks = 800 blocks; c fully scalar so all
// weight loads are s_loads; X loads coalesced, L1/L2-cached across channels.
// ---------------------------------------------------------------------------
__global__ __launch_bounds__(256)
void prep_v(const float* __restrict__ X, const float* __restrict__ Wc,
            const float* __restrict__ bc, const float* __restrict__ WV_task,
            const float* __restrict__ BV_task, unsigned short* __restrict__ VG) {
    int c = blockIdx.x / 25;                        // 0..31 (scalar)
    int p = (blockIdx.x % 25) * 256 + threadIdx.x;
    int x0 = p / 80, y0 = p % 80;
    const float* wb = Wc + c * 576;
    float acc = 0.f;
    for (int dx = -1; dx <= 1; ++dx) {
        int xx = x0 + dx; if (xx < 0 || xx >= 80) continue;
        for (int dy = -1; dy <= 1; ++dy) {
            int yy = y0 + dy; if (yy < 0 || yy >= 80) continue;
            int pos = (dx + 1) * 3 + (dy + 1);
            const float* xp = X + xx * 80 + yy;
#pragma unroll 16
            for (int i = 0; i < 64; ++i)
                acc = fmaf(xp[i * NPIX], wb[i * 9 + pos], acc);
        }
    }
    VG[c * NPIX + p] = f2bf(WV_task[c] * (acc + bc[c]) + BV_task[c]);
}

// ---------------------------------------------------------------------------
// attn_mfma: flash attention, bf16 hi/lo split MFMA, software-pipelined.
// grid = 200 q-tiles(32q) x 4 key-splits.  4 waves = 2 q-subtiles x 2 key-halves.
// Loop: write LDS buf[t&1] -> ONE barrier -> issue loads(t+1) -> compute(t).
// Swizzles: K tile ((row>>1)&7)<<4 (reads use interleaved keys 2li+sub),
// V tile (row&7)<<4.  Both conflict-free (<=2 lanes/slot per quarter-wave).
// ---------------------------------------------------------------------------
__global__ __launch_bounds__(256)
void attn_mfma(const unsigned short* __restrict__ QhG,
               const unsigned short* __restrict__ QlG,
               const unsigned short* __restrict__ KhG,
               const unsigned short* __restrict__ KlG,
               const unsigned short* __restrict__ VG,
               float* __restrict__ PmG, float* __restrict__ PlG,
               unsigned short* __restrict__ PaccG) {
    __shared__ __align__(16) char lds[46080];
    // buf0: 0..20479 (Kh 0..8191, Kl 8192..16383, V 16384..20479)
    // buf1: 20480..40959;  P: 40960..46079 (4 waves x 16 rows x 80 B)

    const int tid = threadIdx.x;
    const int w = tid >> 6, l = tid & 63;
    const int g = l >> 4, li = l & 15;
    const int qt = blockIdx.x >> 2, ks4 = blockIdx.x & 3;
    const int qs = w >> 1, kh = w & 1;
    const int qbase = qt * 32 + qs * 16;
    const int kbase = ks4 * KEYS_PER_SPLIT;

    // ---- Q fragments from precomputed global (4 x 16B) ----
    s8v qh[2], ql[2];
    {
        const unsigned short* qb = QhG + (qbase + li) * 64 + g * 8;
        qh[0] = *(const s8v*)(qb);
        qh[1] = *(const s8v*)(qb + 32);
        const unsigned short* qb2 = QlG + (qbase + li) * 64 + g * 8;
        ql[0] = *(const s8v*)(qb2);
        ql[1] = *(const s8v*)(qb2 + 32);
    }

    // ---- loop-invariant LDS offsets ----
    int kaddr[2][2];
#pragma unroll
    for (int sub = 0; sub < 2; ++sub) {
        int key = kh * 32 + li * 2 + sub;
        int swz = (li & 7) << 4;                 // == ((key>>1)&7)<<4
#pragma unroll
        for (int kc = 0; kc < 2; ++kc)
            kaddr[sub][kc] = key * 128 + ((g * 16 + kc * 64) ^ swz);
    }
    const int vswz = (li & 7) << 4;
    const int vaddr0 = 16384 + li * 128 + ((kh * 64 + g * 16) ^ vswz);
    const int vaddr1 = 16384 + (li + 16) * 128 + ((kh * 64 + g * 16) ^ vswz);
    char* pldsw = lds + 40960 + w * 1280;
    const int pw_store = (4 * g) * 80 + li * 4;
    const int pr_addr  = li * 80 + g * 16;
    const int r0 = tid >> 3, c0 = (tid & 7) * 16;
    const int st_k0 = r0 * 128 + (c0 ^ (((r0 >> 1) & 7) << 4));
    const int r1 = 32 + r0;
    const int st_k1 = r1 * 128 + (c0 ^ (((r1 >> 1) & 7) << 4));
    const int vc = tid >> 3, vwi = (tid & 7) * 16;
    const int st_v = 16384 + vc * 128 + (vwi ^ ((vc & 7) << 4));
    const unsigned short* kgp = KhG + (long)kbase * 64 + tid * 8;
    const unsigned short* klp = KlG + (long)kbase * 64 + tid * 8;
    const unsigned short* vgp = VG + vc * NPIX + kbase + (vwi >> 1);

    f4v acc0 = {0.f, 0.f, 0.f, 0.f}, acc1 = {0.f, 0.f, 0.f, 0.f};
    float m[4]    = {-INFINITY, -INFINITY, -INFINITY, -INFINITY};
    float lsum[4] = {0.f, 0.f, 0.f, 0.f};

    // prologue: loads for tile 0
    s8v rkh0 = *(const s8v*)(kgp);
    s8v rkh1 = *(const s8v*)(kgp + 2048);
    s8v rkl0 = *(const s8v*)(klp);
    s8v rkl1 = *(const s8v*)(klp + 2048);
    s8v rv   = *(const s8v*)(vgp);

    for (int t = 0; t < TILES_PER_SPLIT; ++t) {
        char* buf = lds + (t & 1) * 20480;
        *(s8v*)(buf + st_k0) = rkh0;
        *(s8v*)(buf + st_k1) = rkh1;
        *(s8v*)(buf + 8192 + st_k0) = rkl0;
        *(s8v*)(buf + 8192 + st_k1) = rkl1;
        *(s8v*)(buf + st_v) = rv;
        __syncthreads();

        if (t + 1 < TILES_PER_SPLIT) {          // prefetch next tile into regs
            kgp += 4096; klp += 4096; vgp += 64;
            rkh0 = *(const s8v*)(kgp);
            rkh1 = *(const s8v*)(kgp + 2048);
            rkl0 = *(const s8v*)(klp);
            rkl1 = *(const s8v*)(klp + 2048);
            rv   = *(const s8v*)(vgp);
        }

        // ---- QK^T (interleaved key cols: s0 -> key 2li, s1 -> key 2li+1) ----
        f4v s0 = {0.f, 0.f, 0.f, 0.f}, s1 = {0.f, 0.f, 0.f, 0.f};
#pragma unroll
        for (int kc = 0; kc < 2; ++kc) {
            s8v kf0 = *(const s8v*)(buf + kaddr[0][kc]);
            s8v kg0 = *(const s8v*)(buf + 8192 + kaddr[0][kc]);
            s8v kf1 = *(const s8v*)(buf + kaddr[1][kc]);
            s8v kg1 = *(const s8v*)(buf + 8192 + kaddr[1][kc]);
            s0 = __builtin_amdgcn_mfma_f32_16x16x32_bf16(qh[kc], kf0, s0, 0, 0, 0);
            s0 = __builtin_amdgcn_mfma_f32_16x16x32_bf16(qh[kc], kg0, s0, 0, 0, 0);
            s0 = __builtin_amdgcn_mfma_f32_16x16x32_bf16(ql[kc], kf0, s0, 0, 0, 0);
            s1 = __builtin_amdgcn_mfma_f32_16x16x32_bf16(qh[kc], kf1, s1, 0, 0, 0);
            s1 = __builtin_amdgcn_mfma_f32_16x16x32_bf16(qh[kc], kg1, s1, 0, 0, 0);
            s1 = __builtin_amdgcn_mfma_f32_16x16x32_bf16(ql[kc], kf1, s1, 0, 0, 0);
        }

        // ---- online softmax (deferred lsum, conditional rescale) ----
        float mx[4];
#pragma unroll
        for (int r = 0; r < 4; ++r) {
            float v = fmaxf(s0[r], s1[r]);
            ROWRED16_MAX(v);
            mx[r] = v;
        }
        if (__any((mx[0] > m[0]) | (mx[1] > m[1]) | (mx[2] > m[2]) | (mx[3] > m[3]))) {
#pragma unroll
            for (int r = 0; r < 4; ++r) {
                float mn = fmaxf(m[r], mx[r]);
                float sc = __expf(m[r] - mn);
                lsum[r] *= sc; acc0[r] *= sc; acc1[r] *= sc; m[r] = mn;
            }
        }
#pragma unroll
        for (int r = 0; r < 4; ++r) {
            float p0 = __expf(s0[r] - m[r]);
            float p1 = __expf(s1[r] - m[r]);
            lsum[r] += p0 + p1;
            unsigned pk = (__float_as_uint(p0) >> 16) | (__float_as_uint(p1) & 0xffff0000u);
            *(unsigned*)(pldsw + pw_store + r * 80) = pk;
        }

        // ---- PV ----
        s8v pf = *(const s8v*)(pldsw + pr_addr);
        s8v v0 = *(const s8v*)(buf + vaddr0);
        s8v v1 = *(const s8v*)(buf + vaddr1);
        acc0 = __builtin_amdgcn_mfma_f32_16x16x32_bf16(pf, v0, acc0, 0, 0, 0);
        acc1 = __builtin_amdgcn_mfma_f32_16x16x32_bf16(pf, v1, acc1, 0, 0, 0);
    }

    // ---- finalize per-row l, then in-block merge of key-half wave pairs ----
#pragma unroll
    for (int r = 0; r < 4; ++r) { ROWRED16_SUM(lsum[r]); }

    __syncthreads();
    float* macc = (float*)lds;           // [4 waves][16 q][32 c]
    float* mmm  = (float*)(lds + 8192);  // [4][16]
    float* mll  = (float*)(lds + 8448);  // [4][16]
#pragma unroll
    for (int r = 0; r < 4; ++r) {
        macc[w * 512 + (4 * g + r) * 32 + li]      = acc0[r];
        macc[w * 512 + (4 * g + r) * 32 + 16 + li] = acc1[r];
        if (li == 0) { mmm[w * 16 + 4 * g + r] = m[r]; mll[w * 16 + 4 * g + r] = lsum[r]; }
    }
    __syncthreads();
#pragma unroll
    for (int rep = 0; rep < 4; ++rep) {
        int idx = rep * 256 + tid;                  // < 1024
        int qs2 = idx >> 9, qq = (idx >> 5) & 15, c = idx & 31;
        int w0 = qs2 * 2, w1 = w0 + 1;
        float m0 = mmm[w0 * 16 + qq], m1 = mmm[w1 * 16 + qq];
        float M = fmaxf(m0, m1);
        float e0 = __expf(m0 - M), e1 = __expf(m1 - M);
        float L = mll[w0 * 16 + qq] * e0 + mll[w1 * 16 + qq] * e1;
        float A = macc[w0 * 512 + qq * 32 + c] * e0 + macc[w1 * 512 + qq * 32 + c] * e1;
        int qg = qt * 32 + qs2 * 16 + qq;
        PaccG[ks4 * 204800 + qg * 32 + c] = f2bf(A);
        if (c == 0) { PmG[ks4 * NPIX + qg] = M; PlG[ks4 * NPIX + qg] = L; }
    }
}

// ---------------------------------------------------------------------------
__global__ __launch_bounds__(256)
void merge_out(const float* __restrict__ Pm, const float* __restrict__ Pl,
               const unsigned short* __restrict__ Pacc, float* __restrict__ out) {
    int idx = blockIdx.x * 256 + threadIdx.x;       // < 204800
    int q = idx >> 5, c = idx & 31;
    float m0 = Pm[q], m1 = Pm[NPIX + q], m2 = Pm[2 * NPIX + q], m3 = Pm[3 * NPIX + q];
    float M = fmaxf(fmaxf(m0, m1), fmaxf(m2, m3));
    float e0 = __expf(m0 - M), e1 = __expf(m1 - M), e2 = __expf(m2 - M), e3 = __expf(m3 - M);
    float den = Pl[q] * e0 + Pl[NPIX + q] * e1 + Pl[2 * NPIX + q] * e2 + Pl[3 * NPIX + q] * e3;
    float num = bf2f(Pacc[q * 32 + c]) * e0 + bf2f(Pacc[204800 + q * 32 + c]) * e1
              + bf2f(Pacc[409600 + q * 32 + c]) * e2 + bf2f(Pacc[614400 + q * 32 + c]) * e3;
    out[c * NPIX + q] = num / den;
}

// ---------------------------------------------------------------------------
extern "C" void kernel_launch(void* const* d_in, const int* in_sizes, int n_in,
                              void* d_out, int out_size, void* d_ws, size_t ws_size,
                              hipStream_t stream) {
    const float* X       = (const float*)d_in[0];
    const float* WQ_task = (const float*)d_in[1];
    const float* BQ_task = (const float*)d_in[2];
    const float* WK_task = (const float*)d_in[3];
    const float* BK_task = (const float*)d_in[4];
    const float* WV_task = (const float*)d_in[5];
    const float* BV_task = (const float*)d_in[6];
    const float* WQ_tm1  = (const float*)d_in[7];
    const float* WQ_x    = (const float*)d_in[8];
    const float* BQ      = (const float*)d_in[9];
    const float* WK_x    = (const float*)d_in[10];
    const float* BK      = (const float*)d_in[11];
    const float* prev_Q  = (const float*)d_in[12];
    const float* Vconv_w = (const float*)d_in[13];
    const float* Vconv_b = (const float*)d_in[14];

    char* wsb = (char*)d_ws;
    unsigned short* QhG  = (unsigned short*)(wsb + 0);        //  819200
    unsigned short* QlG  = (unsigned short*)(wsb + 819200);   //  819200
    unsigned short* KhG  = (unsigned short*)(wsb + 1638400);  //  819200
    unsigned short* KlG  = (unsigned short*)(wsb + 2457600);  //  819200
    unsigned short* VG   = (unsigned short*)(wsb + 3276800);  //  409600
    float*          PmG  = (float*)(wsb + 3686400);           //  102400
    float*          PlG  = (float*)(wsb + 3788800);           //  102400
    unsigned short* PaccG= (unsigned short*)(wsb + 3891200);  // 1638400 -> 5529600 total

    prep_qk<<<400, 256, 0, stream>>>(X, prev_Q, WQ_task, BQ_task, WQ_tm1, WQ_x, BQ,
                                     WK_task, BK_task, WK_x, BK, QhG, QlG, KhG, KlG);
    prep_v<<<800, 256, 0, stream>>>(X, Vconv_w, Vconv_b, WV_task, BV_task, VG);
    attn_mfma<<<800, 256, 0, stream>>>(QhG, QlG, KhG, KlG, VG, PmG, PlG, PaccG);
    merge_out<<<800, 256, 0, stream>>>(PmG, PlG, PaccG, (float*)d_out);
}

// Round 5
// 89.598 us; speedup vs baseline: 24.2607x; 1.0741x over previous
//
#include <hip/hip_runtime.h>
#include <math.h>

#define NPIX  6400
#define NH    8
#define KSPLIT 5
#define KPS   1280        // keys per split
#define KPW   320         // keys per wave
#define TPW   10          // 32-key tiles per wave

typedef __attribute__((ext_vector_type(8)))  short s8v;    // 8 bf16
typedef __attribute__((ext_vector_type(16))) float f16v;
typedef __attribute__((ext_vector_type(4)))  float f4v;
typedef __attribute__((ext_vector_type(4)))  int   i4v;

__device__ __forceinline__ unsigned short f2bf(float f) {
    unsigned int u = __float_as_uint(f);
    unsigned int r = (u + 0x7fffu + ((u >> 16) & 1u)) >> 16;   // RNE
    return (unsigned short)r;
}
__device__ __forceinline__ float bf2f(unsigned short h) {
    return __uint_as_float(((unsigned int)h) << 16);
}
__device__ __forceinline__ f16v zero16() {
    f16v z = {0,0,0,0,0,0,0,0,0,0,0,0,0,0,0,0};
    return z;
}

// ---------------------------------------------------------------------------
// prep_fused:
//  blocks 0..399  : Qs (head-summed Q) and K, hi/lo bf16, stored [pixel][64f]
//  blocks 400..1199: V = WV_task*(conv3x3(X)+b)+BV_task, bf16, stored [c][pixel]
// ---------------------------------------------------------------------------
__global__ __launch_bounds__(256)
void prep_fused(const float* __restrict__ X, const float* __restrict__ prevQ,
                const float* __restrict__ WQ_task, const float* __restrict__ BQ_task,
                const float* __restrict__ WQ_tm1, const float* __restrict__ WQ_x,
                const float* __restrict__ BQ,
                const float* __restrict__ WK_task, const float* __restrict__ BK_task,
                const float* __restrict__ WK_x, const float* __restrict__ BK,
                const float* __restrict__ Wc, const float* __restrict__ bc,
                const float* __restrict__ WV_task, const float* __restrict__ BV_task,
                unsigned short* __restrict__ QhG, unsigned short* __restrict__ QlG,
                unsigned short* __restrict__ KhG, unsigned short* __restrict__ KlG,
                unsigned short* __restrict__ VG) {
    int bid = blockIdx.x;
    if (bid < 400) {
        int fg = bid / 25;                          // 0..15 (4 features each)
        int p  = (bid % 25) * 256 + threadIdx.x;
        unsigned short qh_[4], ql_[4], kh_[4], kl_[4];
#pragma unroll
        for (int j = 0; j < 4; ++j) {
            int f = fg * 4 + j;
            float x = X[f * NPIX + p];
            float kv = WK_task[f] * (WK_x[f] * x + BK[f]) + BK_task[f];
            unsigned short khb = f2bf(kv);
            kh_[j] = khb;
            kl_[j] = f2bf(kv - bf2f(khb));
            float wqx_x = WQ_x[f] * x;
            float a = 0.f;
#pragma unroll
            for (int h = 0; h < NH; ++h) {
                int hf = h * 64 + f;
                float inner = WQ_tm1[hf] * prevQ[hf * NPIX + p] + wqx_x + BQ[hf];
                a += WQ_task[hf] * inner + BQ_task[hf];
            }
            unsigned short qhb = f2bf(a);
            qh_[j] = qhb;
            ql_[j] = f2bf(a - bf2f(qhb));
        }
        *(ushort4*)(QhG + p * 64 + fg * 4) = *(ushort4*)qh_;
        *(ushort4*)(QlG + p * 64 + fg * 4) = *(ushort4*)ql_;
        *(ushort4*)(KhG + p * 64 + fg * 4) = *(ushort4*)kh_;
        *(ushort4*)(KlG + p * 64 + fg * 4) = *(ushort4*)kl_;
    } else {
        int b2 = bid - 400;
        int c = b2 / 25;                            // 0..31 (scalar per block)
        int p = (b2 % 25) * 256 + threadIdx.x;
        int x0 = p / 80, y0 = p % 80;
        const float* wb = Wc + c * 576;
        float acc = 0.f;
        for (int dx = -1; dx <= 1; ++dx) {
            int xx = x0 + dx; if (xx < 0 || xx >= 80) continue;
            for (int dy = -1; dy <= 1; ++dy) {
                int yy = y0 + dy; if (yy < 0 || yy >= 80) continue;
                int pos = (dx + 1) * 3 + (dy + 1);
                const float* xp = X + xx * 80 + yy;
#pragma unroll 16
                for (int i = 0; i < 64; ++i)
                    acc = fmaf(xp[i * NPIX], wb[i * 9 + pos], acc);
            }
        }
        VG[c * NPIX + p] = f2bf(WV_task[c] * (acc + bc[c]) + BV_task[c]);
    }
}

// ---------------------------------------------------------------------------
// attn_mfma: LDS-free flash attention, swapped 32x32x16 MFMA.
// grid = 200 q-tiles(32q) x 5 key-splits = 1000 blocks, 4 independent waves.
// Wave w owns keys [ks*1280 + w*320, +320), processes 10 tiles of 32 keys.
// Per tile: D[k][q] = K·Qs^T via 12 MFMA (hi/lo split, 4 f-chunks);
// lane owns q = lane&31, half the k-rows -> in-lane softmax (+1 shfl_xor 32);
// P packed to bf16 (v_cvt_pk_bf16_f32) + shfl_xor(32) -> B-frag for PV:
// O[c][q] += V·P via 2 MFMA.  No LDS, no barriers in the loop.
// Epilogue: 4-wave merge in LDS, write per-split partials.
// ---------------------------------------------------------------------------
__global__ __launch_bounds__(256)
void attn_mfma(const unsigned short* __restrict__ QhG,
               const unsigned short* __restrict__ QlG,
               const unsigned short* __restrict__ KhG,
               const unsigned short* __restrict__ KlG,
               const unsigned short* __restrict__ VG,
               float* __restrict__ PmG, float* __restrict__ PlG,
               unsigned short* __restrict__ PaccG) {
    __shared__ __align__(16) char lds[17408];   // macc 16384 | mm 512 | ll 512

    const int tid = threadIdx.x;
    const int w = tid >> 6, l = tid & 63;
    const int lq = l & 31, h = l >> 5;
    const int qt = blockIdx.x / KSPLIT, ks = blockIdx.x % KSPLIT;
    const int qbase = qt * 32;
    const int wkbase = ks * KPS + w * KPW;

    // Q fragments: B-operand, col=q=lane&31, f = chunk*16 + h*8 + j
    s8v qh[4], ql[4];
    {
        const unsigned short* qp  = QhG + (qbase + lq) * 64 + h * 8;
        const unsigned short* qp2 = QlG + (qbase + lq) * 64 + h * 8;
#pragma unroll
        for (int c = 0; c < 4; ++c) {
            qh[c] = *(const s8v*)(qp  + c * 16);
            ql[c] = *(const s8v*)(qp2 + c * 16);
        }
    }

    const unsigned short* kh_base = KhG + (wkbase + lq) * 64 + h * 8;
    const unsigned short* kl_base = KlG + (wkbase + lq) * 64 + h * 8;
    const unsigned short* v_base  = VG + lq * NPIX + wkbase + h * 8;

    f16v o = zero16();
    float m = -INFINITY, lsum = 0.f;

    for (int t = 0; t < TPW; ++t) {
        const unsigned short* kp = kh_base + t * 32 * 64;
        const unsigned short* lp = kl_base + t * 32 * 64;
        s8v ka0 = *(const s8v*)(kp +  0);
        s8v ka1 = *(const s8v*)(kp + 16);
        s8v ka2 = *(const s8v*)(kp + 32);
        s8v ka3 = *(const s8v*)(kp + 48);
        s8v kb0 = *(const s8v*)(lp +  0);
        s8v kb1 = *(const s8v*)(lp + 16);
        s8v kb2 = *(const s8v*)(lp + 32);
        s8v kb3 = *(const s8v*)(lp + 48);
        s8v v0  = *(const s8v*)(v_base + t * 32);
        s8v v1  = *(const s8v*)(v_base + t * 32 + 16);

        // ---- QK^T (swapped): s[k][q], hi*hi + hi*lo + lo*hi ----
        f16v s = zero16();
        s = __builtin_amdgcn_mfma_f32_32x32x16_bf16(ka0, qh[0], s, 0, 0, 0);
        s = __builtin_amdgcn_mfma_f32_32x32x16_bf16(ka0, ql[0], s, 0, 0, 0);
        s = __builtin_amdgcn_mfma_f32_32x32x16_bf16(kb0, qh[0], s, 0, 0, 0);
        s = __builtin_amdgcn_mfma_f32_32x32x16_bf16(ka1, qh[1], s, 0, 0, 0);
        s = __builtin_amdgcn_mfma_f32_32x32x16_bf16(ka1, ql[1], s, 0, 0, 0);
        s = __builtin_amdgcn_mfma_f32_32x32x16_bf16(kb1, qh[1], s, 0, 0, 0);
        s = __builtin_amdgcn_mfma_f32_32x32x16_bf16(ka2, qh[2], s, 0, 0, 0);
        s = __builtin_amdgcn_mfma_f32_32x32x16_bf16(ka2, ql[2], s, 0, 0, 0);
        s = __builtin_amdgcn_mfma_f32_32x32x16_bf16(kb2, qh[2], s, 0, 0, 0);
        s = __builtin_amdgcn_mfma_f32_32x32x16_bf16(ka3, qh[3], s, 0, 0, 0);
        s = __builtin_amdgcn_mfma_f32_32x32x16_bf16(ka3, ql[3], s, 0, 0, 0);
        s = __builtin_amdgcn_mfma_f32_32x32x16_bf16(kb3, qh[3], s, 0, 0, 0);

        // ---- in-lane online softmax (lane owns one q, 16 of 32 k) ----
        float mx = fmaxf(fmaxf(fmaxf(s[0], s[1]), fmaxf(s[2], s[3])),
                         fmaxf(fmaxf(s[4], s[5]), fmaxf(s[6], s[7])));
        mx = fmaxf(mx, fmaxf(fmaxf(fmaxf(s[8], s[9]), fmaxf(s[10], s[11])),
                             fmaxf(fmaxf(s[12], s[13]), fmaxf(s[14], s[15]))));
        mx = fmaxf(mx, __shfl_xor(mx, 32));
        if (__any(mx > m)) {
            float mn = fmaxf(m, mx);
            float sc = __expf(m - mn);
            lsum *= sc;
#pragma unroll
            for (int r = 0; r < 16; ++r) o[r] *= sc;
            m = mn;
        }
        float pv[16];
#pragma unroll
        for (int r = 0; r < 16; ++r) pv[r] = __expf(s[r] - m);
        float ps = ((pv[0] + pv[1]) + (pv[2] + pv[3])) + ((pv[4] + pv[5]) + (pv[6] + pv[7]))
                 + ((pv[8] + pv[9]) + (pv[10] + pv[11])) + ((pv[12] + pv[13]) + (pv[14] + pv[15]));
        lsum += ps + __shfl_xor(ps, 32);

        // ---- pack P to bf16 pairs, redistribute halves, build B-frags ----
        unsigned pk0, pk1, pk2, pk3, pk4, pk5, pk6, pk7;
        asm("v_cvt_pk_bf16_f32 %0, %1, %2" : "=v"(pk0) : "v"(pv[0]),  "v"(pv[1]));
        asm("v_cvt_pk_bf16_f32 %0, %1, %2" : "=v"(pk1) : "v"(pv[2]),  "v"(pv[3]));
        asm("v_cvt_pk_bf16_f32 %0, %1, %2" : "=v"(pk2) : "v"(pv[4]),  "v"(pv[5]));
        asm("v_cvt_pk_bf16_f32 %0, %1, %2" : "=v"(pk3) : "v"(pv[6]),  "v"(pv[7]));
        asm("v_cvt_pk_bf16_f32 %0, %1, %2" : "=v"(pk4) : "v"(pv[8]),  "v"(pv[9]));
        asm("v_cvt_pk_bf16_f32 %0, %1, %2" : "=v"(pk5) : "v"(pv[10]), "v"(pv[11]));
        asm("v_cvt_pk_bf16_f32 %0, %1, %2" : "=v"(pk6) : "v"(pv[12]), "v"(pv[13]));
        asm("v_cvt_pk_bf16_f32 %0, %1, %2" : "=v"(pk7) : "v"(pv[14]), "v"(pv[15]));
        unsigned ot0 = (unsigned)__shfl_xor((int)pk0, 32);
        unsigned ot1 = (unsigned)__shfl_xor((int)pk1, 32);
        unsigned ot2 = (unsigned)__shfl_xor((int)pk2, 32);
        unsigned ot3 = (unsigned)__shfl_xor((int)pk3, 32);
        unsigned ot4 = (unsigned)__shfl_xor((int)pk4, 32);
        unsigned ot5 = (unsigned)__shfl_xor((int)pk5, 32);
        unsigned ot6 = (unsigned)__shfl_xor((int)pk6, 32);
        unsigned ot7 = (unsigned)__shfl_xor((int)pk7, 32);
        // chunk0 needs k = h*8 + 0..7 ; chunk1 needs k = 16 + h*8 + 0..7
        i4v b0v = { h ? (int)ot2 : (int)pk0, h ? (int)ot3 : (int)pk1,
                    h ? (int)pk2 : (int)ot0, h ? (int)pk3 : (int)ot1 };
        i4v b1v = { h ? (int)ot6 : (int)pk4, h ? (int)ot7 : (int)pk5,
                    h ? (int)pk6 : (int)ot4, h ? (int)pk7 : (int)ot5 };
        s8v pb0 = __builtin_bit_cast(s8v, b0v);
        s8v pb1 = __builtin_bit_cast(s8v, b1v);

        // ---- PV: O[c][q] += V[c][k] * P[k][q] ----
        o = __builtin_amdgcn_mfma_f32_32x32x16_bf16(v0, pb0, o, 0, 0, 0);
        o = __builtin_amdgcn_mfma_f32_32x32x16_bf16(v1, pb1, o, 0, 0, 0);
    }

    // ---- 4-wave merge via LDS ----
    float* mm = (float*)(lds + 16384);
    float* ll = (float*)(lds + 16896);
#pragma unroll
    for (int rg = 0; rg < 4; ++rg) {
        f4v val = { o[rg * 4 + 0], o[rg * 4 + 1], o[rg * 4 + 2], o[rg * 4 + 3] };
        int cb = rg * 8 + 4 * h;                              // channel base
        int byte = (w * 32 + lq) * 128 + ((cb * 4) ^ ((lq & 7) << 4));
        *(f4v*)(lds + byte) = val;
    }
    if (l < 32) { mm[w * 32 + lq] = m; ll[w * 32 + lq] = lsum; }
    __syncthreads();

    {
        int q = tid >> 3, cb = (tid & 7) * 4;
        float m0 = mm[q], m1 = mm[32 + q], m2 = mm[64 + q], m3 = mm[96 + q];
        float M = fmaxf(fmaxf(m0, m1), fmaxf(m2, m3));
        float e0 = __expf(m0 - M), e1 = __expf(m1 - M);
        float e2 = __expf(m2 - M), e3 = __expf(m3 - M);
        float L = ll[q] * e0 + ll[32 + q] * e1 + ll[64 + q] * e2 + ll[96 + q] * e3;
        int swz = (q & 7) << 4;
        f4v a0 = *(f4v*)(lds + (0 * 32 + q) * 128 + ((cb * 4) ^ swz));
        f4v a1 = *(f4v*)(lds + (1 * 32 + q) * 128 + ((cb * 4) ^ swz));
        f4v a2 = *(f4v*)(lds + (2 * 32 + q) * 128 + ((cb * 4) ^ swz));
        f4v a3 = *(f4v*)(lds + (3 * 32 + q) * 128 + ((cb * 4) ^ swz));
        int qg = qbase + q;
        ushort4 outp;
        outp.x = f2bf(a0[0] * e0 + a1[0] * e1 + a2[0] * e2 + a3[0] * e3);
        outp.y = f2bf(a0[1] * e0 + a1[1] * e1 + a2[1] * e2 + a3[1] * e3);
        outp.z = f2bf(a0[2] * e0 + a1[2] * e1 + a2[2] * e2 + a3[2] * e3);
        outp.w = f2bf(a0[3] * e0 + a1[3] * e1 + a2[3] * e2 + a3[3] * e3);
        *(ushort4*)(PaccG + ks * 204800 + qg * 32 + cb) = outp;
        if ((tid & 7) == 0) { PmG[ks * NPIX + qg] = M; PlG[ks * NPIX + qg] = L; }
    }
}

// ---------------------------------------------------------------------------
__global__ __launch_bounds__(256)
void merge_out(const float* __restrict__ Pm, const float* __restrict__ Pl,
               const unsigned short* __restrict__ Pacc, float* __restrict__ out) {
    int idx = blockIdx.x * 256 + threadIdx.x;       // < 204800
    int q = idx >> 5, c = idx & 31;
    float mv[KSPLIT];
    float M = -INFINITY;
#pragma unroll
    for (int ksi = 0; ksi < KSPLIT; ++ksi) { mv[ksi] = Pm[ksi * NPIX + q]; M = fmaxf(M, mv[ksi]); }
    float den = 0.f, num = 0.f;
#pragma unroll
    for (int ksi = 0; ksi < KSPLIT; ++ksi) {
        float e = __expf(mv[ksi] - M);
        den += Pl[ksi * NPIX + q] * e;
        num += bf2f(Pacc[ksi * 204800 + q * 32 + c]) * e;
    }
    out[c * NPIX + q] = num / den;
}

// ---------------------------------------------------------------------------
extern "C" void kernel_launch(void* const* d_in, const int* in_sizes, int n_in,
                              void* d_out, int out_size, void* d_ws, size_t ws_size,
                              hipStream_t stream) {
    const float* X       = (const float*)d_in[0];
    const float* WQ_task = (const float*)d_in[1];
    const float* BQ_task = (const float*)d_in[2];
    const float* WK_task = (const float*)d_in[3];
    const float* BK_task = (const float*)d_in[4];
    const float* WV_task = (const float*)d_in[5];
    const float* BV_task = (const float*)d_in[6];
    const float* WQ_tm1  = (const float*)d_in[7];
    const float* WQ_x    = (const float*)d_in[8];
    const float* BQ      = (const float*)d_in[9];
    const float* WK_x    = (const float*)d_in[10];
    const float* BK      = (const float*)d_in[11];
    const float* prev_Q  = (const float*)d_in[12];
    const float* Vconv_w = (const float*)d_in[13];
    const float* Vconv_b = (const float*)d_in[14];

    char* wsb = (char*)d_ws;
    unsigned short* QhG  = (unsigned short*)(wsb + 0);        //  819200
    unsigned short* QlG  = (unsigned short*)(wsb + 819200);   //  819200
    unsigned short* KhG  = (unsigned short*)(wsb + 1638400);  //  819200
    unsigned short* KlG  = (unsigned short*)(wsb + 2457600);  //  819200
    unsigned short* VG   = (unsigned short*)(wsb + 3276800);  //  409600
    float*          PmG  = (float*)(wsb + 3686400);           //  128000
    float*          PlG  = (float*)(wsb + 3814400);           //  128000
    unsigned short* PaccG= (unsigned short*)(wsb + 3942400);  // 2048000 -> 5990400 total

    prep_fused<<<1200, 256, 0, stream>>>(X, prev_Q, WQ_task, BQ_task, WQ_tm1, WQ_x, BQ,
                                         WK_task, BK_task, WK_x, BK,
                                         Vconv_w, Vconv_b, WV_task, BV_task,
                                         QhG, QlG, KhG, KlG, VG);
    attn_mfma<<<1000, 256, 0, stream>>>(QhG, QlG, KhG, KlG, VG, PmG, PlG, PaccG);
    merge_out<<<800, 256, 0, stream>>>(PmG, PlG, PaccG, (float*)d_out);
}

// Round 7
// 66.610 us; speedup vs baseline: 32.6332x; 1.3451x over previous
//
#include <hip/hip_runtime.h>
#include <math.h>

#define NPIX  6400
#define NH    8
#define KSPLIT 5
#define KPS   1280        // keys per split
#define KPW   320         // keys per wave
#define DITER 5           // double-tile iterations (64 keys each)

typedef _Float16 f16x8 __attribute__((ext_vector_type(8)));
typedef _Float16 f16x4 __attribute__((ext_vector_type(4)));
typedef __fp16   h16x2 __attribute__((ext_vector_type(2)));   // native cvt_pkrtz type
typedef __attribute__((ext_vector_type(16))) float f16v;
typedef __attribute__((ext_vector_type(4)))  float f4v;
typedef __attribute__((ext_vector_type(4)))  int   i4v;
typedef unsigned int u32x2 __attribute__((ext_vector_type(2)));

__device__ __forceinline__ f16v zero16() {
    f16v z = {0,0,0,0,0,0,0,0,0,0,0,0,0,0,0,0};
    return z;
}
__device__ __forceinline__ unsigned pkrtz(float a, float b) {
    h16x2 h = __builtin_amdgcn_cvt_pkrtz(a, b);
    return __builtin_bit_cast(unsigned, h);
}
// both-halves exchange via permlane32_swap (VALU pipe, no LDS):
__device__ __forceinline__ float xhalf_max(float x) {
    unsigned a = __float_as_uint(x), b = a;
    u32x2 r = __builtin_amdgcn_permlane32_swap(a, b, false, false);
    return fmaxf(__uint_as_float(r[0]), __uint_as_float(r[1]));
}
__device__ __forceinline__ float xhalf_sum(float x) {
    unsigned a = __float_as_uint(x), b = a;
    u32x2 r = __builtin_amdgcn_permlane32_swap(a, b, false, false);
    return __uint_as_float(r[0]) + __uint_as_float(r[1]);
}
#define PL32SWAP(a, b) { u32x2 _r = __builtin_amdgcn_permlane32_swap((a), (b), false, false); (a) = _r[0]; (b) = _r[1]; }

// ---------------------------------------------------------------------------
// prep_fused:
//  blocks 0..799  : Qs (head-summed) and K -> fp16, stored [pixel][64f] (2 f/thread)
//  blocks 800..1199: V = WV_task*(conv3x3(X)+b)+BV_task -> fp16 [c][pixel] (2 c/thread)
// ---------------------------------------------------------------------------
__global__ __launch_bounds__(256)
void prep_fused(const float* __restrict__ X, const float* __restrict__ prevQ,
                const float* __restrict__ WQ_task, const float* __restrict__ BQ_task,
                const float* __restrict__ WQ_tm1, const float* __restrict__ WQ_x,
                const float* __restrict__ BQ,
                const float* __restrict__ WK_task, const float* __restrict__ BK_task,
                const float* __restrict__ WK_x, const float* __restrict__ BK,
                const float* __restrict__ Wc, const float* __restrict__ bc,
                const float* __restrict__ WV_task, const float* __restrict__ BV_task,
                _Float16* __restrict__ QG, _Float16* __restrict__ KG,
                _Float16* __restrict__ VG) {
    int bid = blockIdx.x;
    if (bid < 800) {
        int f0 = (bid / 25) * 2;                    // 0,2,..,62
        int p  = (bid % 25) * 256 + threadIdx.x;
        float qv[2], kv[2];
#pragma unroll
        for (int j = 0; j < 2; ++j) {
            int f = f0 + j;
            float x = X[f * NPIX + p];
            kv[j] = WK_task[f] * (WK_x[f] * x + BK[f]) + BK_task[f];
            float wqx_x = WQ_x[f] * x;
            float a = 0.f;
#pragma unroll
            for (int h = 0; h < NH; ++h) {
                int hf = h * 64 + f;
                float inner = WQ_tm1[hf] * prevQ[hf * NPIX + p] + wqx_x + BQ[hf];
                a += WQ_task[hf] * inner + BQ_task[hf];
            }
            qv[j] = a;
        }
        _Float16 q0 = (_Float16)qv[0], q1 = (_Float16)qv[1];
        _Float16 k0 = (_Float16)kv[0], k1 = (_Float16)kv[1];
        QG[p * 64 + f0] = q0; QG[p * 64 + f0 + 1] = q1;
        KG[p * 64 + f0] = k0; KG[p * 64 + f0 + 1] = k1;
    } else {
        int b2 = bid - 800;
        int c0 = (b2 / 25) * 2;                     // 0,2,..,30 (scalar)
        int p  = (b2 % 25) * 256 + threadIdx.x;
        int x0 = p / 80, y0 = p % 80;
        const float* wb0 = Wc + c0 * 576;
        const float* wb1 = Wc + (c0 + 1) * 576;
        float acc0 = 0.f, acc1 = 0.f;
        for (int dx = -1; dx <= 1; ++dx) {
            int xx = x0 + dx; if (xx < 0 || xx >= 80) continue;
            for (int dy = -1; dy <= 1; ++dy) {
                int yy = y0 + dy; if (yy < 0 || yy >= 80) continue;
                int pos = (dx + 1) * 3 + (dy + 1);
                const float* xp = X + xx * 80 + yy;
#pragma unroll 16
                for (int i = 0; i < 64; ++i) {
                    float xv = xp[i * NPIX];
                    acc0 = fmaf(xv, wb0[i * 9 + pos], acc0);
                    acc1 = fmaf(xv, wb1[i * 9 + pos], acc1);
                }
            }
        }
        VG[c0 * NPIX + p]       = (_Float16)(WV_task[c0] * (acc0 + bc[c0]) + BV_task[c0]);
        VG[(c0 + 1) * NPIX + p] = (_Float16)(WV_task[c0 + 1] * (acc1 + bc[c0 + 1]) + BV_task[c0 + 1]);
    }
}

// ---------------------------------------------------------------------------
// attn_mfma: LDS-free, shuffle-free flash attention, fp16 32x32x16 MFMA,
// two 32-key tiles per iteration (independent QK chains, joint softmax).
// grid = 200 q-tiles(32q) x 5 key-splits = 1000 blocks, 4 independent waves.
// Cross-half reduce and P-fragment redistribution via v_permlane32_swap_b32.
// ---------------------------------------------------------------------------
__global__ __launch_bounds__(256, 4)
void attn_mfma(const _Float16* __restrict__ QG,
               const _Float16* __restrict__ KG,
               const _Float16* __restrict__ VG,
               float* __restrict__ PmG, float* __restrict__ PlG,
               _Float16* __restrict__ PaccG) {
    __shared__ __align__(16) char lds[17408];   // macc 16384 | mm 512 | ll 512

    const int tid = threadIdx.x;
    const int w = tid >> 6, l = tid & 63;
    const int lq = l & 31, h = l >> 5;
    const int qt = blockIdx.x / KSPLIT, ks = blockIdx.x % KSPLIT;
    const int qbase = qt * 32;
    const int wkbase = ks * KPS + w * KPW;

    // Q fragments (B-operand): col=q=lane&31, k=f=(chunk*16 + h*8 + j)
    f16x8 qf[4];
    {
        const _Float16* qp = QG + (qbase + lq) * 64 + h * 8;
#pragma unroll
        for (int c = 0; c < 4; ++c) qf[c] = *(const f16x8*)(qp + c * 16);
    }

    const _Float16* kg = KG + (wkbase + lq) * 64 + h * 8;
    const _Float16* vg = VG + lq * NPIX + wkbase + h * 8;

    f16v o = zero16();
    float m = -INFINITY, lsum = 0.f;

    for (int it = 0; it < DITER; ++it) {
        // ---- loads: tiles A (keys +0..31) and B (keys +32..63) ----
        f16x8 kA0 = *(const f16x8*)(kg +  0);
        f16x8 kA1 = *(const f16x8*)(kg + 16);
        f16x8 kA2 = *(const f16x8*)(kg + 32);
        f16x8 kA3 = *(const f16x8*)(kg + 48);
        f16x8 kB0 = *(const f16x8*)(kg + 2048);
        f16x8 kB1 = *(const f16x8*)(kg + 2064);
        f16x8 kB2 = *(const f16x8*)(kg + 2080);
        f16x8 kB3 = *(const f16x8*)(kg + 2096);
        f16x8 vA0 = *(const f16x8*)(vg +  0);
        f16x8 vA1 = *(const f16x8*)(vg + 16);
        f16x8 vB0 = *(const f16x8*)(vg + 32);
        f16x8 vB1 = *(const f16x8*)(vg + 48);
        kg += 4096; vg += 64;

        // ---- QK^T (swapped): s[k][q], two independent 4-MFMA chains ----
        f16v sA = zero16(), sB = zero16();
        sA = __builtin_amdgcn_mfma_f32_32x32x16_f16(kA0, qf[0], sA, 0, 0, 0);
        sB = __builtin_amdgcn_mfma_f32_32x32x16_f16(kB0, qf[0], sB, 0, 0, 0);
        sA = __builtin_amdgcn_mfma_f32_32x32x16_f16(kA1, qf[1], sA, 0, 0, 0);
        sB = __builtin_amdgcn_mfma_f32_32x32x16_f16(kB1, qf[1], sB, 0, 0, 0);
        sA = __builtin_amdgcn_mfma_f32_32x32x16_f16(kA2, qf[2], sA, 0, 0, 0);
        sB = __builtin_amdgcn_mfma_f32_32x32x16_f16(kB2, qf[2], sB, 0, 0, 0);
        sA = __builtin_amdgcn_mfma_f32_32x32x16_f16(kA3, qf[3], sA, 0, 0, 0);
        sB = __builtin_amdgcn_mfma_f32_32x32x16_f16(kB3, qf[3], sB, 0, 0, 0);

        // ---- joint online softmax over 64 keys (tree + permlane cross-half) ----
        float t8[8];
#pragma unroll
        for (int r = 0; r < 8; ++r)
            t8[r] = fmaxf(fmaxf(sA[2 * r], sA[2 * r + 1]),
                          fmaxf(sB[2 * r], sB[2 * r + 1]));
        float mx = fmaxf(fmaxf(fmaxf(t8[0], t8[1]), fmaxf(t8[2], t8[3])),
                         fmaxf(fmaxf(t8[4], t8[5]), fmaxf(t8[6], t8[7])));
        mx = xhalf_max(mx);
        if (__any(mx > m)) {
            float mn = fmaxf(m, mx);
            float sc = __expf(m - mn);
            lsum *= sc;
#pragma unroll
            for (int r = 0; r < 16; ++r) o[r] *= sc;
            m = mn;
        }
        float pA[16], pB[16];
#pragma unroll
        for (int r = 0; r < 16; ++r) pA[r] = __expf(sA[r] - m);
#pragma unroll
        for (int r = 0; r < 16; ++r) pB[r] = __expf(sB[r] - m);
        float ps = 0.f;
#pragma unroll
        for (int r = 0; r < 16; ++r) ps += pA[r] + pB[r];
        lsum += xhalf_sum(ps);

        // ---- pack P->fp16 pairs; permlane32_swap builds both B-frag regs ----
        {
            unsigned p0 = pkrtz(pA[0],  pA[1]),  p1 = pkrtz(pA[2],  pA[3]);
            unsigned p2 = pkrtz(pA[4],  pA[5]),  p3 = pkrtz(pA[6],  pA[7]);
            unsigned p4 = pkrtz(pA[8],  pA[9]),  p5 = pkrtz(pA[10], pA[11]);
            unsigned p6 = pkrtz(pA[12], pA[13]), p7 = pkrtz(pA[14], pA[15]);
            PL32SWAP(p0, p2); PL32SWAP(p1, p3); PL32SWAP(p4, p6); PL32SWAP(p5, p7);
            i4v f0 = { (int)p0, (int)p1, (int)p2, (int)p3 };
            i4v f1 = { (int)p4, (int)p5, (int)p6, (int)p7 };
            o = __builtin_amdgcn_mfma_f32_32x32x16_f16(vA0, __builtin_bit_cast(f16x8, f0), o, 0, 0, 0);
            o = __builtin_amdgcn_mfma_f32_32x32x16_f16(vA1, __builtin_bit_cast(f16x8, f1), o, 0, 0, 0);
        }
        {
            unsigned p0 = pkrtz(pB[0],  pB[1]),  p1 = pkrtz(pB[2],  pB[3]);
            unsigned p2 = pkrtz(pB[4],  pB[5]),  p3 = pkrtz(pB[6],  pB[7]);
            unsigned p4 = pkrtz(pB[8],  pB[9]),  p5 = pkrtz(pB[10], pB[11]);
            unsigned p6 = pkrtz(pB[12], pB[13]), p7 = pkrtz(pB[14], pB[15]);
            PL32SWAP(p0, p2); PL32SWAP(p1, p3); PL32SWAP(p4, p6); PL32SWAP(p5, p7);
            i4v f0 = { (int)p0, (int)p1, (int)p2, (int)p3 };
            i4v f1 = { (int)p4, (int)p5, (int)p6, (int)p7 };
            o = __builtin_amdgcn_mfma_f32_32x32x16_f16(vB0, __builtin_bit_cast(f16x8, f0), o, 0, 0, 0);
            o = __builtin_amdgcn_mfma_f32_32x32x16_f16(vB1, __builtin_bit_cast(f16x8, f1), o, 0, 0, 0);
        }
    }

    // ---- 4-wave merge via LDS ----
    float* mm = (float*)(lds + 16384);
    float* ll = (float*)(lds + 16896);
#pragma unroll
    for (int rg = 0; rg < 4; ++rg) {
        f4v val = { o[rg * 4 + 0], o[rg * 4 + 1], o[rg * 4 + 2], o[rg * 4 + 3] };
        int cb = rg * 8 + 4 * h;                              // channel base
        int byte = (w * 32 + lq) * 128 + ((cb * 4) ^ ((lq & 7) << 4));
        *(f4v*)(lds + byte) = val;
    }
    if (l < 32) { mm[w * 32 + lq] = m; ll[w * 32 + lq] = lsum; }
    __syncthreads();

    {
        int q = tid >> 3, cb = (tid & 7) * 4;
        float m0 = mm[q], m1 = mm[32 + q], m2 = mm[64 + q], m3 = mm[96 + q];
        float M = fmaxf(fmaxf(m0, m1), fmaxf(m2, m3));
        float e0 = __expf(m0 - M), e1 = __expf(m1 - M);
        float e2 = __expf(m2 - M), e3 = __expf(m3 - M);
        float L = ll[q] * e0 + ll[32 + q] * e1 + ll[64 + q] * e2 + ll[96 + q] * e3;
        int swz = (q & 7) << 4;
        f4v a0 = *(f4v*)(lds + (0 * 32 + q) * 128 + ((cb * 4) ^ swz));
        f4v a1 = *(f4v*)(lds + (1 * 32 + q) * 128 + ((cb * 4) ^ swz));
        f4v a2 = *(f4v*)(lds + (2 * 32 + q) * 128 + ((cb * 4) ^ swz));
        f4v a3 = *(f4v*)(lds + (3 * 32 + q) * 128 + ((cb * 4) ^ swz));
        int qg = qbase + q;
        f16x4 outp;
        outp[0] = (_Float16)(a0[0] * e0 + a1[0] * e1 + a2[0] * e2 + a3[0] * e3);
        outp[1] = (_Float16)(a0[1] * e0 + a1[1] * e1 + a2[1] * e2 + a3[1] * e3);
        outp[2] = (_Float16)(a0[2] * e0 + a1[2] * e1 + a2[2] * e2 + a3[2] * e3);
        outp[3] = (_Float16)(a0[3] * e0 + a1[3] * e1 + a2[3] * e2 + a3[3] * e3);
        *(f16x4*)(PaccG + ks * 204800 + qg * 32 + cb) = outp;
        if ((tid & 7) == 0) { PmG[ks * NPIX + qg] = M; PlG[ks * NPIX + qg] = L; }
    }
}

// ---------------------------------------------------------------------------
__global__ __launch_bounds__(256)
void merge_out(const float* __restrict__ Pm, const float* __restrict__ Pl,
               const _Float16* __restrict__ Pacc, float* __restrict__ out) {
    int idx = blockIdx.x * 256 + threadIdx.x;       // < 204800
    int q = idx >> 5, c = idx & 31;
    float mv[KSPLIT];
    float M = -INFINITY;
#pragma unroll
    for (int ksi = 0; ksi < KSPLIT; ++ksi) { mv[ksi] = Pm[ksi * NPIX + q]; M = fmaxf(M, mv[ksi]); }
    float den = 0.f, num = 0.f;
#pragma unroll
    for (int ksi = 0; ksi < KSPLIT; ++ksi) {
        float e = __expf(mv[ksi] - M);
        den += Pl[ksi * NPIX + q] * e;
        num += (float)Pacc[ksi * 204800 + q * 32 + c] * e;
    }
    out[c * NPIX + q] = num / den;
}

// ---------------------------------------------------------------------------
extern "C" void kernel_launch(void* const* d_in, const int* in_sizes, int n_in,
                              void* d_out, int out_size, void* d_ws, size_t ws_size,
                              hipStream_t stream) {
    const float* X       = (const float*)d_in[0];
    const float* WQ_task = (const float*)d_in[1];
    const float* BQ_task = (const float*)d_in[2];
    const float* WK_task = (const float*)d_in[3];
    const float* BK_task = (const float*)d_in[4];
    const float* WV_task = (const float*)d_in[5];
    const float* BV_task = (const float*)d_in[6];
    const float* WQ_tm1  = (const float*)d_in[7];
    const float* WQ_x    = (const float*)d_in[8];
    const float* BQ      = (const float*)d_in[9];
    const float* WK_x    = (const float*)d_in[10];
    const float* BK      = (const float*)d_in[11];
    const float* prev_Q  = (const float*)d_in[12];
    const float* Vconv_w = (const float*)d_in[13];
    const float* Vconv_b = (const float*)d_in[14];

    char* wsb = (char*)d_ws;
    _Float16* QG   = (_Float16*)(wsb + 0);        //  819200
    _Float16* KG   = (_Float16*)(wsb + 819200);   //  819200
    _Float16* VG   = (_Float16*)(wsb + 1638400);  //  409600
    float*    PmG  = (float*)(wsb + 2048000);     //  128000
    float*    PlG  = (float*)(wsb + 2176000);     //  128000
    _Float16* PaccG= (_Float16*)(wsb + 2304000);  // 2048000 -> 4352000 total

    prep_fused<<<1200, 256, 0, stream>>>(X, prev_Q, WQ_task, BQ_task, WQ_tm1, WQ_x, BQ,
                                         WK_task, BK_task, WK_x, BK,
                                         Vconv_w, Vconv_b, WV_task, BV_task,
                                         QG, KG, VG);
    attn_mfma<<<1000, 256, 0, stream>>>(QG, KG, VG, PmG, PlG, PaccG);
    merge_out<<<800, 256, 0, stream>>>(PmG, PlG, PaccG, (float*)d_out);
}

// Round 8
// 66.301 us; speedup vs baseline: 32.7853x; 1.0047x over previous
//
#include <hip/hip_runtime.h>
#include <math.h>

#define NPIX  6400
#define NH    8
#define KSPLIT 5
#define KPS   1280        // keys per split
#define KPW   320         // keys per wave
#define DITER 5           // double-tile iterations (64 keys each)
#define LOG2E 1.4426950408889634f
#define DEFER_THR 11.5f   // log2-units (~8 nats)

typedef _Float16 f16x8 __attribute__((ext_vector_type(8)));
typedef _Float16 f16x4 __attribute__((ext_vector_type(4)));
typedef __fp16   h16x2 __attribute__((ext_vector_type(2)));   // native cvt_pkrtz type
typedef __attribute__((ext_vector_type(16))) float f16v;
typedef __attribute__((ext_vector_type(4)))  float f4v;
typedef __attribute__((ext_vector_type(4)))  int   i4v;
typedef unsigned int u32x2 __attribute__((ext_vector_type(2)));

__device__ __forceinline__ f16v zero16() {
    f16v z = {0,0,0,0,0,0,0,0,0,0,0,0,0,0,0,0};
    return z;
}
__device__ __forceinline__ float exp2fast(float x) {
    float r;
    asm("v_exp_f32 %0, %1" : "=v"(r) : "v"(x));
    return r;
}
__device__ __forceinline__ unsigned pkrtz(float a, float b) {
    h16x2 h = __builtin_amdgcn_cvt_pkrtz(a, b);
    return __builtin_bit_cast(unsigned, h);
}
// both-halves exchange via permlane32_swap (VALU pipe, no LDS):
__device__ __forceinline__ float xhalf_max(float x) {
    unsigned a = __float_as_uint(x), b = a;
    u32x2 r = __builtin_amdgcn_permlane32_swap(a, b, false, false);
    return fmaxf(__uint_as_float(r[0]), __uint_as_float(r[1]));
}
__device__ __forceinline__ float xhalf_sum(float x) {
    unsigned a = __float_as_uint(x), b = a;
    u32x2 r = __builtin_amdgcn_permlane32_swap(a, b, false, false);
    return __uint_as_float(r[0]) + __uint_as_float(r[1]);
}
#define PL32SWAP(a, b) { u32x2 _r = __builtin_amdgcn_permlane32_swap((a), (b), false, false); (a) = _r[0]; (b) = _r[1]; }

// ---------------------------------------------------------------------------
// prep_fused (unchanged from round 7, except Q scaled by log2(e)):
//  blocks 0..799  : Qs (head-summed) and K -> fp16, stored [pixel][64f]
//  blocks 800..1199: V = WV_task*(conv3x3(X)+b)+BV_task -> fp16 [c][pixel]
// ---------------------------------------------------------------------------
__global__ __launch_bounds__(256)
void prep_fused(const float* __restrict__ X, const float* __restrict__ prevQ,
                const float* __restrict__ WQ_task, const float* __restrict__ BQ_task,
                const float* __restrict__ WQ_tm1, const float* __restrict__ WQ_x,
                const float* __restrict__ BQ,
                const float* __restrict__ WK_task, const float* __restrict__ BK_task,
                const float* __restrict__ WK_x, const float* __restrict__ BK,
                const float* __restrict__ Wc, const float* __restrict__ bc,
                const float* __restrict__ WV_task, const float* __restrict__ BV_task,
                _Float16* __restrict__ QG, _Float16* __restrict__ KG,
                _Float16* __restrict__ VG) {
    int bid = blockIdx.x;
    if (bid < 800) {
        int f0 = (bid / 25) * 2;                    // 0,2,..,62
        int p  = (bid % 25) * 256 + threadIdx.x;
        float qv[2], kv[2];
#pragma unroll
        for (int j = 0; j < 2; ++j) {
            int f = f0 + j;
            float x = X[f * NPIX + p];
            kv[j] = WK_task[f] * (WK_x[f] * x + BK[f]) + BK_task[f];
            float wqx_x = WQ_x[f] * x;
            float a = 0.f;
#pragma unroll
            for (int h = 0; h < NH; ++h) {
                int hf = h * 64 + f;
                float inner = WQ_tm1[hf] * prevQ[hf * NPIX + p] + wqx_x + BQ[hf];
                a += WQ_task[hf] * inner + BQ_task[hf];
            }
            qv[j] = a * LOG2E;                      // fold log2(e) for exp2 softmax
        }
        _Float16 q0 = (_Float16)qv[0], q1 = (_Float16)qv[1];
        _Float16 k0 = (_Float16)kv[0], k1 = (_Float16)kv[1];
        QG[p * 64 + f0] = q0; QG[p * 64 + f0 + 1] = q1;
        KG[p * 64 + f0] = k0; KG[p * 64 + f0 + 1] = k1;
    } else {
        int b2 = bid - 800;
        int c0 = (b2 / 25) * 2;                     // 0,2,..,30 (scalar)
        int p  = (b2 % 25) * 256 + threadIdx.x;
        int x0 = p / 80, y0 = p % 80;
        const float* wb0 = Wc + c0 * 576;
        const float* wb1 = Wc + (c0 + 1) * 576;
        float acc0 = 0.f, acc1 = 0.f;
        for (int dx = -1; dx <= 1; ++dx) {
            int xx = x0 + dx; if (xx < 0 || xx >= 80) continue;
            for (int dy = -1; dy <= 1; ++dy) {
                int yy = y0 + dy; if (yy < 0 || yy >= 80) continue;
                int pos = (dx + 1) * 3 + (dy + 1);
                const float* xp = X + xx * 80 + yy;
#pragma unroll 16
                for (int i = 0; i < 64; ++i) {
                    float xv = xp[i * NPIX];
                    acc0 = fmaf(xv, wb0[i * 9 + pos], acc0);
                    acc1 = fmaf(xv, wb1[i * 9 + pos], acc1);
                }
            }
        }
        VG[c0 * NPIX + p]       = (_Float16)(WV_task[c0] * (acc0 + bc[c0]) + BV_task[c0]);
        VG[(c0 + 1) * NPIX + p] = (_Float16)(WV_task[c0 + 1] * (acc1 + bc[c0 + 1]) + BV_task[c0 + 1]);
    }
}

// ---------------------------------------------------------------------------
// attn_mfma: LDS-free flash attention, fp16 32x32x16 MFMA, fully unrolled
// with explicit 2-stage K register double-buffer + early V issue.
// exp2-direct softmax (Q pre-scaled by log2 e), defer-max THR=11.5 log2-units.
// Pacc stored NORMALIZED (A/L) in fp16; merge weights = L * exp2(m - M).
// ---------------------------------------------------------------------------
__global__ __launch_bounds__(256, 3)
void attn_mfma(const _Float16* __restrict__ QG,
               const _Float16* __restrict__ KG,
               const _Float16* __restrict__ VG,
               float* __restrict__ PmG, float* __restrict__ PlG,
               _Float16* __restrict__ PaccG) {
    __shared__ __align__(16) char lds[17408];   // macc 16384 | mm 512 | ll 512

    const int tid = threadIdx.x;
    const int w = tid >> 6, l = tid & 63;
    const int lq = l & 31, h = l >> 5;
    const int qt = blockIdx.x / KSPLIT, ks = blockIdx.x % KSPLIT;
    const int qbase = qt * 32;
    const int wkbase = ks * KPS + w * KPW;

    // Q fragments (B-operand): col=q=lane&31, k=f=(chunk*16 + h*8 + j)
    f16x8 qf[4];
    {
        const _Float16* qp = QG + (qbase + lq) * 64 + h * 8;
#pragma unroll
        for (int c = 0; c < 4; ++c) qf[c] = *(const f16x8*)(qp + c * 16);
    }

    const _Float16* kg = KG + (wkbase + lq) * 64 + h * 8;
    const _Float16* vg = VG + lq * NPIX + wkbase + h * 8;

    f16v o = zero16();
    float m = -INFINITY, lsum = 0.f;

    // prologue: K loads for iteration 0 into slot 0
    f16x8 kA[2][4], kB[2][4];
#pragma unroll
    for (int i = 0; i < 4; ++i) {
        kA[0][i] = *(const f16x8*)(kg + 16 * i);
        kB[0][i] = *(const f16x8*)(kg + 2048 + 16 * i);
    }

#pragma unroll
    for (int it = 0; it < DITER; ++it) {
        const int cur = it & 1, nxt = cur ^ 1;

        // V loads for THIS iter (consumed after softmax, ~300cy cover)
        f16x8 vA0 = *(const f16x8*)(vg +  0);
        f16x8 vA1 = *(const f16x8*)(vg + 16);
        f16x8 vB0 = *(const f16x8*)(vg + 32);
        f16x8 vB1 = *(const f16x8*)(vg + 48);
        vg += 64;

        // K prefetch for NEXT iter (consumed next iteration)
        if (it + 1 < DITER) {
            kg += 4096;
#pragma unroll
            for (int i = 0; i < 4; ++i) {
                kA[nxt][i] = *(const f16x8*)(kg + 16 * i);
                kB[nxt][i] = *(const f16x8*)(kg + 2048 + 16 * i);
            }
        }

        // ---- QK^T (swapped): s[k][q], two independent 4-MFMA chains ----
        f16v sA = zero16(), sB = zero16();
#pragma unroll
        for (int i = 0; i < 4; ++i) {
            sA = __builtin_amdgcn_mfma_f32_32x32x16_f16(kA[cur][i], qf[i], sA, 0, 0, 0);
            sB = __builtin_amdgcn_mfma_f32_32x32x16_f16(kB[cur][i], qf[i], sB, 0, 0, 0);
        }

        // ---- online softmax in log2 units ----
        float t8[8];
#pragma unroll
        for (int r = 0; r < 8; ++r)
            t8[r] = fmaxf(fmaxf(sA[2 * r], sA[2 * r + 1]),
                          fmaxf(sB[2 * r], sB[2 * r + 1]));
        float mx = fmaxf(fmaxf(fmaxf(t8[0], t8[1]), fmaxf(t8[2], t8[3])),
                         fmaxf(fmaxf(t8[4], t8[5]), fmaxf(t8[6], t8[7])));
        mx = xhalf_max(mx);
        if (__any(mx > m + DEFER_THR)) {            // defer-max: rescale rarely
            float mn = fmaxf(m, mx);
            float sc = exp2fast(m - mn);
            lsum *= sc;
#pragma unroll
            for (int r = 0; r < 16; ++r) o[r] *= sc;
            m = mn;
        }
        // P = exp2(s - m), stored back in sA/sB (register reuse)
#pragma unroll
        for (int r = 0; r < 16; ++r) sA[r] = exp2fast(sA[r] - m);
#pragma unroll
        for (int r = 0; r < 16; ++r) sB[r] = exp2fast(sB[r] - m);
        float ps = 0.f;
#pragma unroll
        for (int r = 0; r < 16; ++r) ps += sA[r] + sB[r];
        lsum += xhalf_sum(ps);

        // ---- pack P->fp16 pairs; permlane32_swap builds both B-frag regs ----
        {
            unsigned p0 = pkrtz(sA[0],  sA[1]),  p1 = pkrtz(sA[2],  sA[3]);
            unsigned p2 = pkrtz(sA[4],  sA[5]),  p3 = pkrtz(sA[6],  sA[7]);
            unsigned p4 = pkrtz(sA[8],  sA[9]),  p5 = pkrtz(sA[10], sA[11]);
            unsigned p6 = pkrtz(sA[12], sA[13]), p7 = pkrtz(sA[14], sA[15]);
            PL32SWAP(p0, p2); PL32SWAP(p1, p3); PL32SWAP(p4, p6); PL32SWAP(p5, p7);
            i4v f0 = { (int)p0, (int)p1, (int)p2, (int)p3 };
            i4v f1 = { (int)p4, (int)p5, (int)p6, (int)p7 };
            o = __builtin_amdgcn_mfma_f32_32x32x16_f16(vA0, __builtin_bit_cast(f16x8, f0), o, 0, 0, 0);
            o = __builtin_amdgcn_mfma_f32_32x32x16_f16(vA1, __builtin_bit_cast(f16x8, f1), o, 0, 0, 0);
        }
        {
            unsigned p0 = pkrtz(sB[0],  sB[1]),  p1 = pkrtz(sB[2],  sB[3]);
            unsigned p2 = pkrtz(sB[4],  sB[5]),  p3 = pkrtz(sB[6],  sB[7]);
            unsigned p4 = pkrtz(sB[8],  sB[9]),  p5 = pkrtz(sB[10], sB[11]);
            unsigned p6 = pkrtz(sB[12], sB[13]), p7 = pkrtz(sB[14], sB[15]);
            PL32SWAP(p0, p2); PL32SWAP(p1, p3); PL32SWAP(p4, p6); PL32SWAP(p5, p7);
            i4v f0 = { (int)p0, (int)p1, (int)p2, (int)p3 };
            i4v f1 = { (int)p4, (int)p5, (int)p6, (int)p7 };
            o = __builtin_amdgcn_mfma_f32_32x32x16_f16(vB0, __builtin_bit_cast(f16x8, f0), o, 0, 0, 0);
            o = __builtin_amdgcn_mfma_f32_32x32x16_f16(vB1, __builtin_bit_cast(f16x8, f1), o, 0, 0, 0);
        }
    }

    // ---- 4-wave merge via LDS ----
    float* mm = (float*)(lds + 16384);
    float* ll = (float*)(lds + 16896);
#pragma unroll
    for (int rg = 0; rg < 4; ++rg) {
        f4v val = { o[rg * 4 + 0], o[rg * 4 + 1], o[rg * 4 + 2], o[rg * 4 + 3] };
        int cb = rg * 8 + 4 * h;                              // channel base
        int byte = (w * 32 + lq) * 128 + ((cb * 4) ^ ((lq & 7) << 4));
        *(f4v*)(lds + byte) = val;
    }
    if (l < 32) { mm[w * 32 + lq] = m; ll[w * 32 + lq] = lsum; }
    __syncthreads();

    {
        int q = tid >> 3, cb = (tid & 7) * 4;
        float m0 = mm[q], m1 = mm[32 + q], m2 = mm[64 + q], m3 = mm[96 + q];
        float M = fmaxf(fmaxf(m0, m1), fmaxf(m2, m3));
        float e0 = exp2fast(m0 - M), e1 = exp2fast(m1 - M);
        float e2 = exp2fast(m2 - M), e3 = exp2fast(m3 - M);
        float L = ll[q] * e0 + ll[32 + q] * e1 + ll[64 + q] * e2 + ll[96 + q] * e3;
        float rL = 1.f / L;
        int swz = (q & 7) << 4;
        f4v a0 = *(f4v*)(lds + (0 * 32 + q) * 128 + ((cb * 4) ^ swz));
        f4v a1 = *(f4v*)(lds + (1 * 32 + q) * 128 + ((cb * 4) ^ swz));
        f4v a2 = *(f4v*)(lds + (2 * 32 + q) * 128 + ((cb * 4) ^ swz));
        f4v a3 = *(f4v*)(lds + (3 * 32 + q) * 128 + ((cb * 4) ^ swz));
        int qg = qbase + q;
        f16x4 outp;    // store NORMALIZED partial (A/L): fp16-safe magnitude
        outp[0] = (_Float16)((a0[0] * e0 + a1[0] * e1 + a2[0] * e2 + a3[0] * e3) * rL);
        outp[1] = (_Float16)((a0[1] * e0 + a1[1] * e1 + a2[1] * e2 + a3[1] * e3) * rL);
        outp[2] = (_Float16)((a0[2] * e0 + a1[2] * e1 + a2[2] * e2 + a3[2] * e3) * rL);
        outp[3] = (_Float16)((a0[3] * e0 + a1[3] * e1 + a2[3] * e2 + a3[3] * e3) * rL);
        *(f16x4*)(PaccG + ks * 204800 + qg * 32 + cb) = outp;
        if ((tid & 7) == 0) { PmG[ks * NPIX + qg] = M; PlG[ks * NPIX + qg] = L; }
    }
}

// ---------------------------------------------------------------------------
// merge_out: combine per-split normalized partials with weights L*exp2(m-M)
// ---------------------------------------------------------------------------
__global__ __launch_bounds__(256)
void merge_out(const float* __restrict__ Pm, const float* __restrict__ Pl,
               const _Float16* __restrict__ Pacc, float* __restrict__ out) {
    int idx = blockIdx.x * 256 + threadIdx.x;       // < 204800
    int q = idx >> 5, c = idx & 31;
    float mv[KSPLIT];
    float M = -INFINITY;
#pragma unroll
    for (int ksi = 0; ksi < KSPLIT; ++ksi) { mv[ksi] = Pm[ksi * NPIX + q]; M = fmaxf(M, mv[ksi]); }
    float den = 0.f, num = 0.f;
#pragma unroll
    for (int ksi = 0; ksi < KSPLIT; ++ksi) {
        float wgt = Pl[ksi * NPIX + q] * exp2fast(mv[ksi] - M);
        den += wgt;
        num += (float)Pacc[ksi * 204800 + q * 32 + c] * wgt;
    }
    out[c * NPIX + q] = num / den;
}

// ---------------------------------------------------------------------------
extern "C" void kernel_launch(void* const* d_in, const int* in_sizes, int n_in,
                              void* d_out, int out_size, void* d_ws, size_t ws_size,
                              hipStream_t stream) {
    const float* X       = (const float*)d_in[0];
    const float* WQ_task = (const float*)d_in[1];
    const float* BQ_task = (const float*)d_in[2];
    const float* WK_task = (const float*)d_in[3];
    const float* BK_task = (const float*)d_in[4];
    const float* WV_task = (const float*)d_in[5];
    const float* BV_task = (const float*)d_in[6];
    const float* WQ_tm1  = (const float*)d_in[7];
    const float* WQ_x    = (const float*)d_in[8];
    const float* BQ      = (const float*)d_in[9];
    const float* WK_x    = (const float*)d_in[10];
    const float* BK      = (const float*)d_in[11];
    const float* prev_Q  = (const float*)d_in[12];
    const float* Vconv_w = (const float*)d_in[13];
    const float* Vconv_b = (const float*)d_in[14];

    char* wsb = (char*)d_ws;
    _Float16* QG   = (_Float16*)(wsb + 0);        //  819200
    _Float16* KG   = (_Float16*)(wsb + 819200);   //  819200
    _Float16* VG   = (_Float16*)(wsb + 1638400);  //  409600
    float*    PmG  = (float*)(wsb + 2048000);     //  128000
    float*    PlG  = (float*)(wsb + 2176000);     //  128000
    _Float16* PaccG= (_Float16*)(wsb + 2304000);  // 2048000 -> 4352000 total

    prep_fused<<<1200, 256, 0, stream>>>(X, prev_Q, WQ_task, BQ_task, WQ_tm1, WQ_x, BQ,
                                         WK_task, BK_task, WK_x, BK,
                                         Vconv_w, Vconv_b, WV_task, BV_task,
                                         QG, KG, VG);
    attn_mfma<<<1000, 256, 0, stream>>>(QG, KG, VG, PmG, PlG, PaccG);
    merge_out<<<800, 256, 0, stream>>>(PmG, PlG, PaccG, (float*)d_out);
}